// Round 4
// baseline (854.206 us; speedup 1.0000x reference)
//
#include <hip/hip_runtime.h>

// ---------------------------------------------------------------------------
// AugmentedMemoryScaledDotProductAttention on MI355X (gfx950)
// B=8 H=8 NQ=NK=1024 D_MODEL=1024 DK=DV=128 M=16  (NKM=1040, padded to 1056)
//
// R3b: R3 with the nontemporal-store type fixed (ext_vector f32x4, not HIP
// float4 struct). attn restructure: (a) T14 reg-staging of K/Kl/V with
// issue-early/write-late, (b) XCD swizzle (16 q-blocks of one bh share L2),
// (c) att staged in padded f32 LDS -> 128B-aligned nontemporal f32x4 stores.
// ---------------------------------------------------------------------------

typedef unsigned short u16;
typedef unsigned int   u32;
typedef __bf16  bf16x8 __attribute__((ext_vector_type(8)));
typedef short   s16x8  __attribute__((ext_vector_type(8)));
typedef float   f32x4  __attribute__((ext_vector_type(4)));

#define MFMA_BF16(a, b, c) __builtin_amdgcn_mfma_f32_16x16x32_bf16((a), (b), (c), 0, 0, 0)

#define NB     8
#define NH     8
#define NQS    1024
#define NKS    1024
#define NKM    1040      // NK + M
#define KSP    1056      // padded key stride (NKM rounded to 32)
#define DKV    128
#define DMODEL 1024
#define SCALE_QK 0.088388347648318447f   // 1/sqrt(128)

__device__ __forceinline__ u16 f2bf(float f) {
  unsigned u = __builtin_bit_cast(unsigned, f);
  u += 0x7fffu + ((u >> 16) & 1u);
  return (u16)(u >> 16);
}
__device__ __forceinline__ float bf2f(u16 h) {
  unsigned u = ((unsigned)h) << 16;
  return __builtin_bit_cast(float, u);
}
__device__ __forceinline__ bf16x8 ld_bf8(const u16* p) {
  s16x8 r = *(const s16x8*)p;
  return __builtin_bit_cast(bf16x8, r);
}

// ---------------------------------------------------------------- elementwise
__global__ void split_kernel(const float* __restrict__ in,
                             u16* __restrict__ hi, u16* __restrict__ lo, int n4) {
  for (int i = blockIdx.x * blockDim.x + threadIdx.x; i < n4;
       i += gridDim.x * blockDim.x) {
    float4 v = ((const float4*)in)[i];
    ushort4 h, l;
    h.x = f2bf(v.x); l.x = f2bf(v.x - bf2f(h.x));
    h.y = f2bf(v.y); l.y = f2bf(v.y - bf2f(h.y));
    h.z = f2bf(v.z); l.z = f2bf(v.z - bf2f(h.z));
    h.w = f2bf(v.w); l.w = f2bf(v.w - bf2f(h.w));
    ((ushort4*)hi)[i] = h;
    ((ushort4*)lo)[i] = l;
  }
}

__global__ void cvt_kernel(const float* __restrict__ in, u16* __restrict__ out, int n4) {
  for (int i = blockIdx.x * blockDim.x + threadIdx.x; i < n4;
       i += gridDim.x * blockDim.x) {
    float4 v = ((const float4*)in)[i];
    ushort4 h;
    h.x = f2bf(v.x); h.y = f2bf(v.y); h.z = f2bf(v.z); h.w = f2bf(v.w);
    ((ushort4*)out)[i] = h;
  }
}

// W is (in=1024, out=1024) row-major; write Wt (out, in) row-major.
__global__ void wtrans_split_kernel(const float* __restrict__ w,
                                    u16* __restrict__ th, u16* __restrict__ tl) {
  int idx = blockIdx.x * 256 + threadIdx.x;   // 1M threads
  int i = idx >> 10, o = idx & 1023;
  float v = w[idx];
  u16 hh = f2bf(v);
  th[o * 1024 + i] = hh;
  tl[o * 1024 + i] = f2bf(v - bf2f(hh));
}

__global__ void wtrans_cvt_kernel(const float* __restrict__ w, u16* __restrict__ t) {
  int idx = blockIdx.x * 256 + threadIdx.x;
  int i = idx >> 10, o = idx & 1023;
  t[o * 1024 + i] = f2bf(w[idx]);
}

// memory-slot rows of K (keys 1024..1039 = sqrt(DK)*m_k ; 1040..1055 = 0)
__global__ void mk_fill_kernel(const float* __restrict__ m_k,
                               u16* __restrict__ kh, u16* __restrict__ kl) {
  int idx = blockIdx.x * 256 + threadIdx.x;     // B*H*32*128 = 262144
  int b = idx >> 15, h = (idx >> 12) & 7, ko = (idx >> 7) & 31, dk = idx & 127;
  float v = 0.f;
  if (ko < 16) v = 11.313708498984760f * m_k[ko * 1024 + h * 128 + dk];
  int dst = ((b * 8 + h) * KSP + 1024 + ko) * 128 + dk;
  u16 hh = f2bf(v);
  kh[dst] = hh;
  kl[dst] = f2bf(v - bf2f(hh));
}

// memory-slot keys of V^T (keys 1024..1039 = sqrt(M)*m_v ; 1040..1055 = 0)
__global__ void mv_fill_kernel(const float* __restrict__ m_v, u16* __restrict__ vt) {
  int idx = blockIdx.x * 256 + threadIdx.x;     // B*H*128*32 = 262144
  int b = idx >> 15, h = (idx >> 12) & 7, dv = (idx >> 5) & 127, ko = idx & 31;
  float v = (ko < 16) ? 4.0f * m_v[ko * 1024 + h * 128 + dv] : 0.f;
  vt[((b * 8 + h) * 128 + dv) * KSP + 1024 + ko] = f2bf(v);
}

// mask (int32, !=0 means masked/dead) -> bit words. mbits[(bh*1024+q)*33 + w]
__global__ void maskbits_kernel(const int* __restrict__ mask, u32* __restrict__ mbits) {
  const int lane = threadIdx.x & 63;
  const int nwave = (gridDim.x * blockDim.x) >> 6;
  int wid = (blockIdx.x * blockDim.x + threadIdx.x) >> 6;
  for (int i = wid; i < 1048576; i += nwave) {        // 2^20 groups of 64 keys
    int m = mask[i * 64 + lane];
    unsigned long long bal = __ballot(m != 0);
    int row = i >> 4;                                  // (bh*1024+q)
    int col = (i * 2) & 31;
    if (lane == 0) mbits[row * 33 + col] = (u32)bal;
    else if (lane == 32) mbits[row * 33 + col + 1] = (u32)(bal >> 32);
  }
}

// word 32 of each row: keys 1024..1039 alive, 1040..1055 dead
__global__ void maskfill_kernel(u32* __restrict__ mbits) {
  int idx = blockIdx.x * 256 + threadIdx.x;   // 65536
  mbits[idx * 33 + 32] = 0xFFFF0000u;
}

// ---------------------------------------------------------------------- GEMM
// C(8192x1024) = A(8192x1024) @ B^T where B given as (1024 n-rows x 1024 k) rm.
// 128x128 tile, BK=64, 4 waves (2x2), 4x4 16x16x32 fragments per wave.
__device__ __forceinline__ void stage_tile(const u16* __restrict__ gbase,
                                           u16* sbase, int w, int lane) {
#pragma unroll
  for (int i = 0; i < 4; ++i) {
    const u16* src = gbase + (w * 32 + i * 8 + (lane >> 3)) * 1024 + (lane & 7) * 8;
    u16* dst = sbase + (w * 32 + i * 8) * 64;
    __builtin_amdgcn_global_load_lds(
        (const __attribute__((address_space(1))) void*)src,
        (__attribute__((address_space(3))) void*)dst, 16, 0, 0);
  }
}

enum { EPI_QSPLIT = 0, EPI_KSPLIT = 1, EPI_VT = 2, EPI_OUT = 3 };

template <bool SPLIT, int EPI>
__global__ __launch_bounds__(256)
void gemm_kernel(const u16* __restrict__ Ah, const u16* __restrict__ Al,
                 const u16* __restrict__ Bh, const u16* __restrict__ Bl,
                 const float* __restrict__ bias,
                 u16* __restrict__ oH, u16* __restrict__ oL,
                 float* __restrict__ oF) {
  __shared__ u16 sAh[128 * 64];
  __shared__ u16 sBh[128 * 64];
  __shared__ u16 sAl[128 * 64];
  __shared__ u16 sBl[128 * 64];
  const int lane = threadIdx.x & 63, w = threadIdx.x >> 6;
  const int bm = blockIdx.x & 63, bn = blockIdx.x >> 6;
  const int wr = w >> 1, wc = w & 1;

  f32x4 acc[4][4];
  const f32x4 fz = {0.f, 0.f, 0.f, 0.f};
#pragma unroll
  for (int m = 0; m < 4; ++m)
#pragma unroll
    for (int n = 0; n < 4; ++n) acc[m][n] = fz;

  for (int kt = 0; kt < 16; ++kt) {
    const int kb = kt * 64;
    stage_tile(Ah + bm * 128 * 1024 + kb, sAh, w, lane);
    stage_tile(Bh + bn * 128 * 1024 + kb, sBh, w, lane);
    if constexpr (SPLIT) {
      stage_tile(Al + bm * 128 * 1024 + kb, sAl, w, lane);
      stage_tile(Bl + bn * 128 * 1024 + kb, sBl, w, lane);
    }
    __syncthreads();
    const int ro = lane & 15;
#pragma unroll
    for (int kk = 0; kk < 2; ++kk) {
      const int co = kk * 32 + (lane >> 4) * 8;
      bf16x8 aH[4], bH[4], aL[4], bL[4];
#pragma unroll
      for (int m = 0; m < 4; ++m) {
        aH[m] = ld_bf8(&sAh[(wr * 64 + m * 16 + ro) * 64 + co]);
        if constexpr (SPLIT) aL[m] = ld_bf8(&sAl[(wr * 64 + m * 16 + ro) * 64 + co]);
      }
#pragma unroll
      for (int n = 0; n < 4; ++n) {
        bH[n] = ld_bf8(&sBh[(wc * 64 + n * 16 + ro) * 64 + co]);
        if constexpr (SPLIT) bL[n] = ld_bf8(&sBl[(wc * 64 + n * 16 + ro) * 64 + co]);
      }
#pragma unroll
      for (int m = 0; m < 4; ++m)
#pragma unroll
        for (int n = 0; n < 4; ++n) {
          acc[m][n] = MFMA_BF16(aH[m], bH[n], acc[m][n]);
          if constexpr (SPLIT) {
            acc[m][n] = MFMA_BF16(aH[m], bL[n], acc[m][n]);
            acc[m][n] = MFMA_BF16(aL[m], bH[n], acc[m][n]);
          }
        }
    }
    __syncthreads();
  }

  // epilogue
#pragma unroll
  for (int m = 0; m < 4; ++m)
#pragma unroll
    for (int n = 0; n < 4; ++n) {
      const int row0 = bm * 128 + wr * 64 + m * 16 + ((lane >> 4) << 2);
      const int col = bn * 128 + wc * 64 + n * 16 + (lane & 15);
      const float bv = bias[col];
#pragma unroll
      for (int r = 0; r < 4; ++r) {
        const float y = acc[m][n][r] + bv;
        const int row = row0 + r;
        if constexpr (EPI == EPI_QSPLIT) {
          u16 hh = f2bf(y);
          oH[row * 1024 + col] = hh;
          oL[row * 1024 + col] = f2bf(y - bf2f(hh));
        } else if constexpr (EPI == EPI_KSPLIT) {
          const int b = row >> 10, key = row & 1023;
          const int dst = ((b * 8 + (col >> 7)) * KSP + key) * 128 + (col & 127);
          u16 hh = f2bf(y);
          oH[dst] = hh;
          oL[dst] = f2bf(y - bf2f(hh));
        } else if constexpr (EPI == EPI_VT) {
          const int b = row >> 10, key = row & 1023;
          const int dst = ((b * 8 + (col >> 7)) * 128 + (col & 127)) * KSP + key;
          oH[dst] = f2bf(y);
        } else {
          oF[row * 1024 + col] = y;
        }
      }
    }
}

// ----------------------------------------------------------------- attention
// 4 waves / block, 16 q-rows per wave, 64 q-rows per block. 33 chunks of 32
// keys. T14 reg-staged K/Kl/V (issue c+1 mid-iteration, ds_write at top of
// c+1). XOR-swizzled K LDS; padded f32 sAtt staging for att writeout (128B
// nt f32x4 groups) and PV A-fragments.
__global__ __launch_bounds__(256, 4)
void attn_kernel(const u16* __restrict__ qh, const u16* __restrict__ ql,
                 const u16* __restrict__ kh, const u16* __restrict__ kl,
                 const u16* __restrict__ vt, const u32* __restrict__ mbits,
                 float* __restrict__ att, u16* __restrict__ obuf,
                 float* __restrict__ inv_l) {
  __shared__ __align__(16) u16 sKh[32 * 128];
  __shared__ __align__(16) u16 sKl[32 * 128];
  __shared__ __align__(16) u16 sVt[128 * 40];
  __shared__ __align__(16) float sAtt[4][16][36];   // padded stride 36
  const int tid = threadIdx.x;
  const int lane = tid & 63, w = tid >> 6;

  // XCD swizzle: dispatch d -> XCD d&7 (heuristic); give each XCD 8 whole bh.
  const int d = blockIdx.x;
  const int bh = (d & 7) * 8 + ((d >> 3) >> 4);
  const int qblk = (d >> 3) & 15;
  const int h = bh & 7;
  const int b = bh >> 3;
  const int qrow0 = qblk * 64 + w * 16;       // within NQ
  const int grow0 = b * NQS + qrow0;          // row in (8192 x 1024) Q/O buffers
  const int ro = lane & 15, go = lane >> 4;

  // Q fragments (held for whole kernel)
  bf16x8 qhf[4], qlf[4];
#pragma unroll
  for (int kk = 0; kk < 4; ++kk) {
    const int off = (grow0 + ro) * 1024 + h * 128 + kk * 32 + go * 8;
    qhf[kk] = ld_bf8(&qh[off]);
    qlf[kk] = ld_bf8(&ql[off]);
  }

  const u16* khb = kh + (size_t)bh * KSP * 128;
  const u16* klb = kl + (size_t)bh * KSP * 128;
  const u16* vtb = vt + (size_t)bh * 128 * KSP;
  const u32* mbb = mbits + (size_t)bh * NQS * 33;
  float* attb = att + (size_t)(bh * NQS + qrow0) * NKM;

  // staging geometry (per thread)
  const int r_k  = tid >> 4;               // K row 0..15 (p=0) / +16 (p=1)
  const int cb_k = (tid & 15) * 16;        // K byte col in 256B row
  const u16* kp0 = khb + r_k * 128 + (cb_k >> 1);
  const u16* lp0 = klb + r_k * 128 + (cb_k >> 1);
  const int dk0 = r_k * 256 + (cb_k ^ ((r_k & 7) << 4));   // LDS byte (p=0)
  // V: t = p*256+tid ; row t/5, byte-col (t%5)*16 (col 64 = pad, dummy src)
  int vr[3], vcs[3];
  bool vok[3];
#pragma unroll
  for (int p = 0; p < 3; ++p) {
    const int t = p * 256 + tid;
    vok[p] = (t < 640);
    const int rr = t / 5;
    const int m5 = t - rr * 5;
    vr[p] = rr;
    vcs[p] = (m5 == 4) ? 0 : m5 * 8;       // src col in u16 (pad -> dummy 0)
  }

  const f32x4 fz = {0.f, 0.f, 0.f, 0.f};
  f32x4 oacc[8];
#pragma unroll
  for (int n = 0; n < 8; ++n) oacc[n] = fz;
  float lsum[4] = {0.f, 0.f, 0.f, 0.f};

  // prologue: issue chunk-0 loads into regs
  s16x8 rkh0, rkh1, rkl0, rkl1, rv0, rv1, rv2;
  {
    rkh0 = *(const s16x8*)(kp0);
    rkh1 = *(const s16x8*)(kp0 + 16 * 128);
    rkl0 = *(const s16x8*)(lp0);
    rkl1 = *(const s16x8*)(lp0 + 16 * 128);
    rv0 = *(const s16x8*)(vtb + (size_t)vr[0] * KSP + vcs[0]);
    rv1 = *(const s16x8*)(vtb + (size_t)vr[1] * KSP + vcs[1]);
    if (vok[2]) rv2 = *(const s16x8*)(vtb + (size_t)vr[2] * KSP + vcs[2]);
  }

  for (int c = 0; c < 33; ++c) {
    const int kb = c * 32;
    __syncthreads();                       // LDS of chunk c-1 fully consumed
    // write staged regs (chunk c) to LDS
    *(s16x8*)((char*)sKh + dk0)        = rkh0;
    *(s16x8*)((char*)sKh + dk0 + 4096) = rkh1;
    *(s16x8*)((char*)sKl + dk0)        = rkl0;
    *(s16x8*)((char*)sKl + dk0 + 4096) = rkl1;
    *(s16x8*)((char*)sVt + tid * 16)          = rv0;
    *(s16x8*)((char*)sVt + (256 + tid) * 16)  = rv1;
    if (vok[2]) *(s16x8*)((char*)sVt + (512 + tid) * 16) = rv2;
    // issue next chunk's loads (in flight across compute)
    if (c < 32) {
      const int nkb = (c + 1) * 32;
      rkh0 = *(const s16x8*)(kp0 + nkb * 128);
      rkh1 = *(const s16x8*)(kp0 + (nkb + 16) * 128);
      rkl0 = *(const s16x8*)(lp0 + nkb * 128);
      rkl1 = *(const s16x8*)(lp0 + (nkb + 16) * 128);
      rv0 = *(const s16x8*)(vtb + (size_t)vr[0] * KSP + nkb + vcs[0]);
      rv1 = *(const s16x8*)(vtb + (size_t)vr[1] * KSP + nkb + vcs[1]);
      if (vok[2]) rv2 = *(const s16x8*)(vtb + (size_t)vr[2] * KSP + nkb + vcs[2]);
    }
    __syncthreads();                       // LDS chunk c ready

    u32 mw[4];
#pragma unroll
    for (int r = 0; r < 4; ++r) mw[r] = mbb[(qrow0 + (go << 2) + r) * 33 + c];

#pragma unroll
    for (int t = 0; t < 2; ++t) {
      f32x4 s = fz;
      const int rr = t * 16 + ro;                  // key row in chunk
      const int sw = (rr & 7) << 4;
      __builtin_amdgcn_s_setprio(1);
#pragma unroll
      for (int kk = 0; kk < 4; ++kk) {
        const int off = rr * 256 + ((kk * 64 + go * 16) ^ sw);
        bf16x8 bhf = ld_bf8((const u16*)((const char*)sKh + off));
        bf16x8 blf = ld_bf8((const u16*)((const char*)sKl + off));
        s = MFMA_BF16(qhf[kk], bhf, s);
        s = MFMA_BF16(qhf[kk], blf, s);
        s = MFMA_BF16(qlf[kk], bhf, s);
      }
      __builtin_amdgcn_s_setprio(0);
      const int key_in = t * 16 + ro;
#pragma unroll
      for (int r = 0; r < 4; ++r) {
        const int lrow = (go << 2) + r;
        const float sv = s[r] * SCALE_QK;
        const bool dead = (mw[r] >> key_in) & 1;
        const float e = dead ? 0.f : __expf(sv);
        lsum[r] += e;
        sAtt[w][lrow][t * 16 + ro] = e;
      }
    }

    // att writeout: 4 lanes cover one row's 32 f32 (128B), nontemporal
    {
      const int arow = lane >> 2, cg = lane & 3;
      if (kb + cg * 8 < NKM) {
        f32x4 v0 = *(const f32x4*)&sAtt[w][arow][cg * 8];
        f32x4 v1 = *(const f32x4*)&sAtt[w][arow][cg * 8 + 4];
        float* dst = attb + (size_t)arow * NKM + kb + cg * 8;
        __builtin_nontemporal_store(v0, (f32x4*)dst);
        __builtin_nontemporal_store(v1, (f32x4*)(dst + 4));
      }
    }

    // PV: A fragment (rows=q, cols=key) from sAtt (cvt to bf16), B from sVt
    {
      f32x4 p0 = *(const f32x4*)&sAtt[w][ro][go * 8];
      f32x4 p1 = *(const f32x4*)&sAtt[w][ro][go * 8 + 4];
      s16x8 pr;
      pr[0] = (short)f2bf(p0[0]); pr[1] = (short)f2bf(p0[1]);
      pr[2] = (short)f2bf(p0[2]); pr[3] = (short)f2bf(p0[3]);
      pr[4] = (short)f2bf(p1[0]); pr[5] = (short)f2bf(p1[1]);
      pr[6] = (short)f2bf(p1[2]); pr[7] = (short)f2bf(p1[3]);
      bf16x8 pa = __builtin_bit_cast(bf16x8, pr);
      __builtin_amdgcn_s_setprio(1);
#pragma unroll
      for (int n = 0; n < 8; ++n) {
        bf16x8 vb = ld_bf8((const u16*)((const char*)sVt + (n * 16 + ro) * 80 + go * 16));
        oacc[n] = MFMA_BF16(pa, vb, oacc[n]);
      }
      __builtin_amdgcn_s_setprio(0);
    }
  }

  // row sums: reduce across the 16 lanes of each group
#pragma unroll
  for (int r = 0; r < 4; ++r) {
    lsum[r] += __shfl_xor(lsum[r], 1);
    lsum[r] += __shfl_xor(lsum[r], 2);
    lsum[r] += __shfl_xor(lsum[r], 4);
    lsum[r] += __shfl_xor(lsum[r], 8);
  }
  float inv[4];
#pragma unroll
  for (int r = 0; r < 4; ++r) inv[r] = 1.0f / lsum[r];
  if (ro == 0) {
#pragma unroll
    for (int r = 0; r < 4; ++r)
      inv_l[bh * NQS + qrow0 + (go << 2) + r] = inv[r];
  }
  // write O = oacc / l  (bf16, row = b*NQ+q, col = h*128+dv)
#pragma unroll
  for (int n = 0; n < 8; ++n)
#pragma unroll
    for (int r = 0; r < 4; ++r) {
      const float o = oacc[n][r] * inv[r];
      obuf[(grow0 + (go << 2) + r) * 1024 + h * 128 + n * 16 + ro] = f2bf(o);
    }
}

// att *= 1/l  (68157440 floats = 17039360 float4, 260 float4 per 1040-row)
__global__ void rescale_kernel(float* __restrict__ att, const float* __restrict__ inv_l) {
  const int total = 17039360;
  for (int i = blockIdx.x * blockDim.x + threadIdx.x; i < total;
       i += gridDim.x * blockDim.x) {
    const int row = i / 260;
    const float s = inv_l[row];
    float4 v = ((const float4*)att)[i];
    v.x *= s; v.y *= s; v.z *= s; v.w *= s;
    ((float4*)att)[i] = v;
  }
}

// --------------------------------------------------------------------- launch
extern "C" void kernel_launch(void* const* d_in, const int* in_sizes, int n_in,
                              void* d_out, int out_size, void* d_ws, size_t ws_size,
                              hipStream_t stream) {
  const float* queries = (const float*)d_in[0];
  const float* keys    = (const float*)d_in[1];
  const float* values  = (const float*)d_in[2];
  const int*   mask    = (const int*)d_in[3];
  const float* Wq = (const float*)d_in[4];
  const float* bq = (const float*)d_in[5];
  const float* Wk = (const float*)d_in[6];
  const float* bk = (const float*)d_in[7];
  const float* Wv = (const float*)d_in[8];
  const float* bv = (const float*)d_in[9];
  const float* Wo = (const float*)d_in[10];
  const float* bo = (const float*)d_in[11];
  const float* m_k = (const float*)d_in[12];
  const float* m_v = (const float*)d_in[13];

  if (ws_size < 164888576) return;   // workspace layout below needs ~157.3 MiB

  char* ws = (char*)d_ws;
  u16* xh_q = (u16*)(ws + 0);            // 16 MiB each
  u16* xl_q = (u16*)(ws + 16777216);
  u16* xh_k = (u16*)(ws + 33554432);
  u16* xl_k = (u16*)(ws + 50331648);
  u16* xv   = (u16*)(ws + 67108864);
  u16* wqth = (u16*)(ws + 83886080);     // 2 MiB each
  u16* wqtl = (u16*)(ws + 85983232);
  u16* wkth = (u16*)(ws + 88080384);
  u16* wktl = (u16*)(ws + 90177536);
  u16* wvt  = (u16*)(ws + 92274688);
  u16* wot  = (u16*)(ws + 94371840);
  u16* qh   = (u16*)(ws + 96468992);     // 16 MiB each
  u16* ql   = (u16*)(ws + 113246208);
  u16* kh   = (u16*)(ws + 130023424);    // 64*1056*128*2 = 16.5 MiB each
  u16* kl   = (u16*)(ws + 147324928);
  u16* vt   = (u16*)(ws + 33554432);     // alias xh_k/xl_k (dead after K-proj)
  u16* obuf = (u16*)(ws + 0);            // alias xh_q (dead after Q-proj)
  u32* mbits = (u32*)(ws + 67108864);    // alias xv (dead after V-proj), 8.65 MiB
  float* invl = (float*)(ws + 164626432);

  float* out = (float*)d_out;
  float* att = out + 8388608;

  // 1. input splits / converts
  split_kernel<<<2048, 256, 0, stream>>>(queries, xh_q, xl_q, 2097152);
  split_kernel<<<2048, 256, 0, stream>>>(keys, xh_k, xl_k, 2097152);
  cvt_kernel<<<2048, 256, 0, stream>>>(values, xv, 2097152);
  // 2. weight transposes
  wtrans_split_kernel<<<4096, 256, 0, stream>>>(Wq, wqth, wqtl);
  wtrans_split_kernel<<<4096, 256, 0, stream>>>(Wk, wkth, wktl);
  wtrans_cvt_kernel<<<4096, 256, 0, stream>>>(Wv, wvt);
  wtrans_cvt_kernel<<<4096, 256, 0, stream>>>(Wo, wot);
  // 3. projections
  gemm_kernel<true, EPI_QSPLIT><<<512, 256, 0, stream>>>(xh_q, xl_q, wqth, wqtl, bq, qh, ql, nullptr);
  gemm_kernel<true, EPI_KSPLIT><<<512, 256, 0, stream>>>(xh_k, xl_k, wkth, wktl, bk, kh, kl, nullptr);
  gemm_kernel<false, EPI_VT><<<512, 256, 0, stream>>>(xv, nullptr, wvt, nullptr, bv, vt, nullptr, nullptr);
  // 4. mask bit-pack (mbits aliases xv -- must run after V-proj)
  maskbits_kernel<<<2048, 256, 0, stream>>>(mask, mbits);
  maskfill_kernel<<<256, 256, 0, stream>>>(mbits);
  // 5. memory slots (K rows 1024..1055, V^T keys 1024..1055)
  mk_fill_kernel<<<1024, 256, 0, stream>>>(m_k, kh, kl);
  mv_fill_kernel<<<1024, 256, 0, stream>>>(m_v, vt);
  // 6. attention (unnormalized e to att, normalized O to obuf, 1/l to invl)
  attn_kernel<<<1024, 256, 0, stream>>>(qh, ql, kh, kl, vt, mbits, att, obuf, invl);
  // 7. normalize att in place
  rescale_kernel<<<4096, 256, 0, stream>>>(att, invl);
  // 8. output projection
  gemm_kernel<false, EPI_OUT><<<512, 256, 0, stream>>>(obuf, nullptr, wot, nullptr, bo, nullptr, nullptr, out);
}

// Round 5
// 604.637 us; speedup vs baseline: 1.4128x; 1.4128x over previous
//
#include <hip/hip_runtime.h>

// ---------------------------------------------------------------------------
// AugmentedMemoryScaledDotProductAttention on MI355X (gfx950)
// B=8 H=8 NQ=NK=1024 D_MODEL=1024 DK=DV=128 M=16  (NKM=1040, padded to 1056)
//
// R4: (a) att writeout back to normal (through-L2) f32x4 stores -- R3's
// nontemporal stores caused 3x write + RMW fetch amplification; (b) attn
// blocks doubled to 512 threads / 128 q-rows (halves K/V refetch); (c)
// wtrans kernels LDS-tiled (old version did 2B scatter stores); (d) sAtt
// stride 37 (bank-conflict-free reads).
// ---------------------------------------------------------------------------

typedef unsigned short u16;
typedef unsigned int   u32;
typedef __bf16  bf16x8 __attribute__((ext_vector_type(8)));
typedef short   s16x8  __attribute__((ext_vector_type(8)));
typedef float   f32x4  __attribute__((ext_vector_type(4)));

#define MFMA_BF16(a, b, c) __builtin_amdgcn_mfma_f32_16x16x32_bf16((a), (b), (c), 0, 0, 0)

#define NB     8
#define NH     8
#define NQS    1024
#define NKS    1024
#define NKM    1040      // NK + M
#define KSP    1056      // padded key stride (NKM rounded to 32)
#define DKV    128
#define DMODEL 1024
#define SCALE_QK 0.088388347648318447f   // 1/sqrt(128)

__device__ __forceinline__ u16 f2bf(float f) {
  unsigned u = __builtin_bit_cast(unsigned, f);
  u += 0x7fffu + ((u >> 16) & 1u);
  return (u16)(u >> 16);
}
__device__ __forceinline__ float bf2f(u16 h) {
  unsigned u = ((unsigned)h) << 16;
  return __builtin_bit_cast(float, u);
}
__device__ __forceinline__ bf16x8 ld_bf8(const u16* p) {
  s16x8 r = *(const s16x8*)p;
  return __builtin_bit_cast(bf16x8, r);
}

// ---------------------------------------------------------------- elementwise
__global__ void split_kernel(const float* __restrict__ in,
                             u16* __restrict__ hi, u16* __restrict__ lo, int n4) {
  for (int i = blockIdx.x * blockDim.x + threadIdx.x; i < n4;
       i += gridDim.x * blockDim.x) {
    float4 v = ((const float4*)in)[i];
    ushort4 h, l;
    h.x = f2bf(v.x); l.x = f2bf(v.x - bf2f(h.x));
    h.y = f2bf(v.y); l.y = f2bf(v.y - bf2f(h.y));
    h.z = f2bf(v.z); l.z = f2bf(v.z - bf2f(h.z));
    h.w = f2bf(v.w); l.w = f2bf(v.w - bf2f(h.w));
    ((ushort4*)hi)[i] = h;
    ((ushort4*)lo)[i] = l;
  }
}

__global__ void cvt_kernel(const float* __restrict__ in, u16* __restrict__ out, int n4) {
  for (int i = blockIdx.x * blockDim.x + threadIdx.x; i < n4;
       i += gridDim.x * blockDim.x) {
    float4 v = ((const float4*)in)[i];
    ushort4 h;
    h.x = f2bf(v.x); h.y = f2bf(v.y); h.z = f2bf(v.z); h.w = f2bf(v.w);
    ((ushort4*)out)[i] = h;
  }
}

// LDS-tiled transpose+split: W (in=1024, out=1024) rm -> th/tl (out, in) rm.
__global__ __launch_bounds__(256)
void wtrans_split_kernel(const float* __restrict__ w,
                         u16* __restrict__ th, u16* __restrict__ tl) {
  __shared__ float t[64][65];
  const int bx = blockIdx.x & 15;    // input-row (i) tile
  const int by = blockIdx.x >> 4;    // output-row (o) tile
  const int r = threadIdx.x >> 4, c4 = threadIdx.x & 15;
#pragma unroll
  for (int i = 0; i < 4; ++i) {
    const int row = bx * 64 + r + i * 16;
    float4 v = *(const float4*)&w[row * 1024 + by * 64 + c4 * 4];
    t[r + i * 16][c4 * 4 + 0] = v.x;
    t[r + i * 16][c4 * 4 + 1] = v.y;
    t[r + i * 16][c4 * 4 + 2] = v.z;
    t[r + i * 16][c4 * 4 + 3] = v.w;
  }
  __syncthreads();
  const int l = threadIdx.x & 63, og = threadIdx.x >> 6;
#pragma unroll
  for (int j = 0; j < 16; ++j) {
    const int o_local = og + j * 4;
    const float v = t[l][o_local];
    const int dst = (by * 64 + o_local) * 1024 + bx * 64 + l;
    u16 hh = f2bf(v);
    th[dst] = hh;
    tl[dst] = f2bf(v - bf2f(hh));
  }
}

__global__ __launch_bounds__(256)
void wtrans_cvt_kernel(const float* __restrict__ w, u16* __restrict__ t16) {
  __shared__ float t[64][65];
  const int bx = blockIdx.x & 15;
  const int by = blockIdx.x >> 4;
  const int r = threadIdx.x >> 4, c4 = threadIdx.x & 15;
#pragma unroll
  for (int i = 0; i < 4; ++i) {
    const int row = bx * 64 + r + i * 16;
    float4 v = *(const float4*)&w[row * 1024 + by * 64 + c4 * 4];
    t[r + i * 16][c4 * 4 + 0] = v.x;
    t[r + i * 16][c4 * 4 + 1] = v.y;
    t[r + i * 16][c4 * 4 + 2] = v.z;
    t[r + i * 16][c4 * 4 + 3] = v.w;
  }
  __syncthreads();
  const int l = threadIdx.x & 63, og = threadIdx.x >> 6;
#pragma unroll
  for (int j = 0; j < 16; ++j) {
    const int o_local = og + j * 4;
    t16[(by * 64 + o_local) * 1024 + bx * 64 + l] = f2bf(t[l][o_local]);
  }
}

// memory-slot rows of K (keys 1024..1039 = sqrt(DK)*m_k ; 1040..1055 = 0)
__global__ void mk_fill_kernel(const float* __restrict__ m_k,
                               u16* __restrict__ kh, u16* __restrict__ kl) {
  int idx = blockIdx.x * 256 + threadIdx.x;     // B*H*32*128 = 262144
  int b = idx >> 15, h = (idx >> 12) & 7, ko = (idx >> 7) & 31, dk = idx & 127;
  float v = 0.f;
  if (ko < 16) v = 11.313708498984760f * m_k[ko * 1024 + h * 128 + dk];
  int dst = ((b * 8 + h) * KSP + 1024 + ko) * 128 + dk;
  u16 hh = f2bf(v);
  kh[dst] = hh;
  kl[dst] = f2bf(v - bf2f(hh));
}

// memory-slot keys of V^T (keys 1024..1039 = sqrt(M)*m_v ; 1040..1055 = 0)
__global__ void mv_fill_kernel(const float* __restrict__ m_v, u16* __restrict__ vt) {
  int idx = blockIdx.x * 256 + threadIdx.x;     // B*H*128*32 = 262144
  int b = idx >> 15, h = (idx >> 12) & 7, dv = (idx >> 5) & 127, ko = idx & 31;
  float v = (ko < 16) ? 4.0f * m_v[ko * 1024 + h * 128 + dv] : 0.f;
  vt[((b * 8 + h) * 128 + dv) * KSP + 1024 + ko] = f2bf(v);
}

// mask (int32, !=0 means masked/dead) -> bit words. mbits[(bh*1024+q)*33 + w]
__global__ void maskbits_kernel(const int* __restrict__ mask, u32* __restrict__ mbits) {
  const int lane = threadIdx.x & 63;
  const int nwave = (gridDim.x * blockDim.x) >> 6;
  int wid = (blockIdx.x * blockDim.x + threadIdx.x) >> 6;
  for (int i = wid; i < 1048576; i += nwave) {        // 2^20 groups of 64 keys
    int m = mask[i * 64 + lane];
    unsigned long long bal = __ballot(m != 0);
    int row = i >> 4;                                  // (bh*1024+q)
    int col = (i * 2) & 31;
    if (lane == 0) mbits[row * 33 + col] = (u32)bal;
    else if (lane == 32) mbits[row * 33 + col + 1] = (u32)(bal >> 32);
  }
}

// word 32 of each row: keys 1024..1039 alive, 1040..1055 dead
__global__ void maskfill_kernel(u32* __restrict__ mbits) {
  int idx = blockIdx.x * 256 + threadIdx.x;   // 65536
  mbits[idx * 33 + 32] = 0xFFFF0000u;
}

// ---------------------------------------------------------------------- GEMM
// C(8192x1024) = A(8192x1024) @ B^T where B given as (1024 n-rows x 1024 k) rm.
// 128x128 tile, BK=64, 4 waves (2x2), 4x4 16x16x32 fragments per wave.
__device__ __forceinline__ void stage_tile(const u16* __restrict__ gbase,
                                           u16* sbase, int w, int lane) {
#pragma unroll
  for (int i = 0; i < 4; ++i) {
    const u16* src = gbase + (w * 32 + i * 8 + (lane >> 3)) * 1024 + (lane & 7) * 8;
    u16* dst = sbase + (w * 32 + i * 8) * 64;
    __builtin_amdgcn_global_load_lds(
        (const __attribute__((address_space(1))) void*)src,
        (__attribute__((address_space(3))) void*)dst, 16, 0, 0);
  }
}

enum { EPI_QSPLIT = 0, EPI_KSPLIT = 1, EPI_VT = 2, EPI_OUT = 3 };

template <bool SPLIT, int EPI>
__global__ __launch_bounds__(256)
void gemm_kernel(const u16* __restrict__ Ah, const u16* __restrict__ Al,
                 const u16* __restrict__ Bh, const u16* __restrict__ Bl,
                 const float* __restrict__ bias,
                 u16* __restrict__ oH, u16* __restrict__ oL,
                 float* __restrict__ oF) {
  __shared__ u16 sAh[128 * 64];
  __shared__ u16 sBh[128 * 64];
  __shared__ u16 sAl[128 * 64];
  __shared__ u16 sBl[128 * 64];
  const int lane = threadIdx.x & 63, w = threadIdx.x >> 6;
  const int bm = blockIdx.x & 63, bn = blockIdx.x >> 6;
  const int wr = w >> 1, wc = w & 1;

  f32x4 acc[4][4];
  const f32x4 fz = {0.f, 0.f, 0.f, 0.f};
#pragma unroll
  for (int m = 0; m < 4; ++m)
#pragma unroll
    for (int n = 0; n < 4; ++n) acc[m][n] = fz;

  for (int kt = 0; kt < 16; ++kt) {
    const int kb = kt * 64;
    stage_tile(Ah + bm * 128 * 1024 + kb, sAh, w, lane);
    stage_tile(Bh + bn * 128 * 1024 + kb, sBh, w, lane);
    if constexpr (SPLIT) {
      stage_tile(Al + bm * 128 * 1024 + kb, sAl, w, lane);
      stage_tile(Bl + bn * 128 * 1024 + kb, sBl, w, lane);
    }
    __syncthreads();
    const int ro = lane & 15;
#pragma unroll
    for (int kk = 0; kk < 2; ++kk) {
      const int co = kk * 32 + (lane >> 4) * 8;
      bf16x8 aH[4], bH[4], aL[4], bL[4];
#pragma unroll
      for (int m = 0; m < 4; ++m) {
        aH[m] = ld_bf8(&sAh[(wr * 64 + m * 16 + ro) * 64 + co]);
        if constexpr (SPLIT) aL[m] = ld_bf8(&sAl[(wr * 64 + m * 16 + ro) * 64 + co]);
      }
#pragma unroll
      for (int n = 0; n < 4; ++n) {
        bH[n] = ld_bf8(&sBh[(wc * 64 + n * 16 + ro) * 64 + co]);
        if constexpr (SPLIT) bL[n] = ld_bf8(&sBl[(wc * 64 + n * 16 + ro) * 64 + co]);
      }
#pragma unroll
      for (int m = 0; m < 4; ++m)
#pragma unroll
        for (int n = 0; n < 4; ++n) {
          acc[m][n] = MFMA_BF16(aH[m], bH[n], acc[m][n]);
          if constexpr (SPLIT) {
            acc[m][n] = MFMA_BF16(aH[m], bL[n], acc[m][n]);
            acc[m][n] = MFMA_BF16(aL[m], bH[n], acc[m][n]);
          }
        }
    }
    __syncthreads();
  }

  // epilogue
#pragma unroll
  for (int m = 0; m < 4; ++m)
#pragma unroll
    for (int n = 0; n < 4; ++n) {
      const int row0 = bm * 128 + wr * 64 + m * 16 + ((lane >> 4) << 2);
      const int col = bn * 128 + wc * 64 + n * 16 + (lane & 15);
      const float bv = bias[col];
#pragma unroll
      for (int r = 0; r < 4; ++r) {
        const float y = acc[m][n][r] + bv;
        const int row = row0 + r;
        if constexpr (EPI == EPI_QSPLIT) {
          u16 hh = f2bf(y);
          oH[row * 1024 + col] = hh;
          oL[row * 1024 + col] = f2bf(y - bf2f(hh));
        } else if constexpr (EPI == EPI_KSPLIT) {
          const int b = row >> 10, key = row & 1023;
          const int dst = ((b * 8 + (col >> 7)) * KSP + key) * 128 + (col & 127);
          u16 hh = f2bf(y);
          oH[dst] = hh;
          oL[dst] = f2bf(y - bf2f(hh));
        } else if constexpr (EPI == EPI_VT) {
          const int b = row >> 10, key = row & 1023;
          const int dst = ((b * 8 + (col >> 7)) * 128 + (col & 127)) * KSP + key;
          oH[dst] = f2bf(y);
        } else {
          oF[row * 1024 + col] = y;
        }
      }
    }
}

// ----------------------------------------------------------------- attention
// 8 waves / block (512 thr), 16 q-rows per wave -> 128 q-rows per block.
// 512 blocks (64 bh x 8 qblk). 33 chunks of 32 keys. T14 reg-staged K/Kl/V.
// XOR-swizzled K LDS; sAtt (stride 37) staged f32 att -> normal f32x4 stores.
__global__ __launch_bounds__(512, 4)
void attn_kernel(const u16* __restrict__ qh, const u16* __restrict__ ql,
                 const u16* __restrict__ kh, const u16* __restrict__ kl,
                 const u16* __restrict__ vt, const u32* __restrict__ mbits,
                 float* __restrict__ att, u16* __restrict__ obuf,
                 float* __restrict__ inv_l) {
  __shared__ __align__(16) u16 sKh[32 * 128];
  __shared__ __align__(16) u16 sKl[32 * 128];
  __shared__ __align__(16) u16 sVt[128 * 40];
  __shared__ __align__(16) float sAtt[8][16][37];
  const int tid = threadIdx.x;
  const int lane = tid & 63, w = tid >> 6;

  // XCD swizzle: XCD x owns bh in [x*8, x*8+8), 8 qblks each.
  const int d = blockIdx.x;                  // 512 blocks
  const int j = d >> 3;
  const int bh = (d & 7) * 8 + (j >> 3);
  const int qblk = j & 7;
  const int h = bh & 7;
  const int b = bh >> 3;
  const int qrow0 = qblk * 128 + w * 16;      // within NQ
  const int grow0 = b * NQS + qrow0;          // row in (8192 x 1024) Q/O buffers
  const int ro = lane & 15, go = lane >> 4;

  // Q fragments (held for whole kernel)
  bf16x8 qhf[4], qlf[4];
#pragma unroll
  for (int kk = 0; kk < 4; ++kk) {
    const int off = (grow0 + ro) * 1024 + h * 128 + kk * 32 + go * 8;
    qhf[kk] = ld_bf8(&qh[off]);
    qlf[kk] = ld_bf8(&ql[off]);
  }

  const u16* khb = kh + (size_t)bh * KSP * 128;
  const u16* klb = kl + (size_t)bh * KSP * 128;
  const u16* vtb = vt + (size_t)bh * 128 * KSP;
  const u32* mbb = mbits + (size_t)bh * NQS * 33;
  float* attb = att + (size_t)(bh * NQS + qrow0) * NKM;

  // staging geometry (512 threads): K -> one 16B load each (32 rows x 256B)
  const int r_k  = tid >> 4;               // 0..31
  const int cb_k = (tid & 15) * 16;        // byte col in 256B row
  const u16* kp0 = khb + r_k * 128 + (cb_k >> 1);
  const u16* lp0 = klb + r_k * 128 + (cb_k >> 1);
  const int dk0 = r_k * 256 + (cb_k ^ ((r_k & 7) << 4));
  // V: 640 16B chunks (128 rows x 5); t0 = tid, t1 = 512+tid (tid<128)
  const int t0 = tid, t1 = 512 + tid;
  const bool vok1 = (tid < 128);
  const int vr0 = t0 / 5, vm0 = t0 - vr0 * 5;
  const int vr1 = t1 / 5, vm1 = t1 - vr1 * 5;
  const int vc0 = (vm0 == 4) ? 0 : vm0 * 8;   // u16 col (pad -> dummy)
  const int vc1 = (vm1 == 4) ? 0 : vm1 * 8;

  const f32x4 fz = {0.f, 0.f, 0.f, 0.f};
  f32x4 oacc[8];
#pragma unroll
  for (int n = 0; n < 8; ++n) oacc[n] = fz;
  float lsum[4] = {0.f, 0.f, 0.f, 0.f};

  // prologue: issue chunk-0 loads into regs
  s16x8 rkh, rkl, rv0, rv1;
  rkh = *(const s16x8*)(kp0);
  rkl = *(const s16x8*)(lp0);
  rv0 = *(const s16x8*)(vtb + (size_t)vr0 * KSP + vc0);
  if (vok1) rv1 = *(const s16x8*)(vtb + (size_t)vr1 * KSP + vc1);

  for (int c = 0; c < 33; ++c) {
    const int kb = c * 32;
    __syncthreads();                       // LDS of chunk c-1 fully consumed
    // write staged regs (chunk c) to LDS
    *(s16x8*)((char*)sKh + dk0) = rkh;
    *(s16x8*)((char*)sKl + dk0) = rkl;
    *(s16x8*)((char*)sVt + t0 * 16) = rv0;
    if (vok1) *(s16x8*)((char*)sVt + t1 * 16) = rv1;
    // issue next chunk's loads (in flight across compute)
    if (c < 32) {
      const int nkb = (c + 1) * 32;
      rkh = *(const s16x8*)(kp0 + nkb * 128);
      rkl = *(const s16x8*)(lp0 + nkb * 128);
      rv0 = *(const s16x8*)(vtb + (size_t)vr0 * KSP + nkb + vc0);
      if (vok1) rv1 = *(const s16x8*)(vtb + (size_t)vr1 * KSP + nkb + vc1);
    }
    __syncthreads();                       // LDS chunk c ready

    u32 mw[4];
#pragma unroll
    for (int r = 0; r < 4; ++r) mw[r] = mbb[(qrow0 + (go << 2) + r) * 33 + c];

#pragma unroll
    for (int t = 0; t < 2; ++t) {
      f32x4 s = fz;
      const int rr = t * 16 + ro;                  // key row in chunk
      const int sw = (rr & 7) << 4;
      __builtin_amdgcn_s_setprio(1);
#pragma unroll
      for (int kk = 0; kk < 4; ++kk) {
        const int off = rr * 256 + ((kk * 64 + go * 16) ^ sw);
        bf16x8 bhf = ld_bf8((const u16*)((const char*)sKh + off));
        bf16x8 blf = ld_bf8((const u16*)((const char*)sKl + off));
        s = MFMA_BF16(qhf[kk], bhf, s);
        s = MFMA_BF16(qhf[kk], blf, s);
        s = MFMA_BF16(qlf[kk], bhf, s);
      }
      __builtin_amdgcn_s_setprio(0);
      const int key_in = t * 16 + ro;
#pragma unroll
      for (int r = 0; r < 4; ++r) {
        const int lrow = (go << 2) + r;
        const float sv = s[r] * SCALE_QK;
        const bool dead = (mw[r] >> key_in) & 1;
        const float e = dead ? 0.f : __expf(sv);
        lsum[r] += e;
        sAtt[w][lrow][t * 16 + ro] = e;
      }
    }

    // att writeout: 4 lanes cover one row's 32 f32 (128B), through L2
    {
      const int arow = lane >> 2, cg = lane & 3;
      if (kb + cg * 8 < NKM) {
        f32x4 v0 = *(const f32x4*)&sAtt[w][arow][cg * 8];
        f32x4 v1 = *(const f32x4*)&sAtt[w][arow][cg * 8 + 4];
        float* dst = attb + (size_t)arow * NKM + kb + cg * 8;
        *(f32x4*)dst = v0;
        *(f32x4*)(dst + 4) = v1;
      }
    }

    // PV: A fragment (rows=q, cols=key) from sAtt (cvt to bf16), B from sVt
    {
      f32x4 p0 = *(const f32x4*)&sAtt[w][ro][go * 8];
      f32x4 p1 = *(const f32x4*)&sAtt[w][ro][go * 8 + 4];
      s16x8 pr;
      pr[0] = (short)f2bf(p0[0]); pr[1] = (short)f2bf(p0[1]);
      pr[2] = (short)f2bf(p0[2]); pr[3] = (short)f2bf(p0[3]);
      pr[4] = (short)f2bf(p1[0]); pr[5] = (short)f2bf(p1[1]);
      pr[6] = (short)f2bf(p1[2]); pr[7] = (short)f2bf(p1[3]);
      bf16x8 pa = __builtin_bit_cast(bf16x8, pr);
      __builtin_amdgcn_s_setprio(1);
#pragma unroll
      for (int n = 0; n < 8; ++n) {
        bf16x8 vb = ld_bf8((const u16*)((const char*)sVt + (n * 16 + ro) * 80 + go * 16));
        oacc[n] = MFMA_BF16(pa, vb, oacc[n]);
      }
      __builtin_amdgcn_s_setprio(0);
    }
  }

  // row sums: reduce across the 16 lanes of each group
#pragma unroll
  for (int r = 0; r < 4; ++r) {
    lsum[r] += __shfl_xor(lsum[r], 1);
    lsum[r] += __shfl_xor(lsum[r], 2);
    lsum[r] += __shfl_xor(lsum[r], 4);
    lsum[r] += __shfl_xor(lsum[r], 8);
  }
  float inv[4];
#pragma unroll
  for (int r = 0; r < 4; ++r) inv[r] = 1.0f / lsum[r];
  if (ro == 0) {
#pragma unroll
    for (int r = 0; r < 4; ++r)
      inv_l[bh * NQS + qrow0 + (go << 2) + r] = inv[r];
  }
  // write O = oacc / l  (bf16, row = b*NQ+q, col = h*128+dv)
#pragma unroll
  for (int n = 0; n < 8; ++n)
#pragma unroll
    for (int r = 0; r < 4; ++r) {
      const float o = oacc[n][r] * inv[r];
      obuf[(grow0 + (go << 2) + r) * 1024 + h * 128 + n * 16 + ro] = f2bf(o);
    }
}

// att *= 1/l  (68157440 floats = 17039360 float4, 260 float4 per 1040-row)
__global__ void rescale_kernel(float* __restrict__ att, const float* __restrict__ inv_l) {
  const int total = 17039360;
  for (int i = blockIdx.x * blockDim.x + threadIdx.x; i < total;
       i += gridDim.x * blockDim.x) {
    const int row = i / 260;
    const float s = inv_l[row];
    float4 v = ((const float4*)att)[i];
    v.x *= s; v.y *= s; v.z *= s; v.w *= s;
    ((float4*)att)[i] = v;
  }
}

// --------------------------------------------------------------------- launch
extern "C" void kernel_launch(void* const* d_in, const int* in_sizes, int n_in,
                              void* d_out, int out_size, void* d_ws, size_t ws_size,
                              hipStream_t stream) {
  const float* queries = (const float*)d_in[0];
  const float* keys    = (const float*)d_in[1];
  const float* values  = (const float*)d_in[2];
  const int*   mask    = (const int*)d_in[3];
  const float* Wq = (const float*)d_in[4];
  const float* bq = (const float*)d_in[5];
  const float* Wk = (const float*)d_in[6];
  const float* bk = (const float*)d_in[7];
  const float* Wv = (const float*)d_in[8];
  const float* bv = (const float*)d_in[9];
  const float* Wo = (const float*)d_in[10];
  const float* bo = (const float*)d_in[11];
  const float* m_k = (const float*)d_in[12];
  const float* m_v = (const float*)d_in[13];

  if (ws_size < 164888576) return;   // workspace layout below needs ~157.3 MiB

  char* ws = (char*)d_ws;
  u16* xh_q = (u16*)(ws + 0);            // 16 MiB each
  u16* xl_q = (u16*)(ws + 16777216);
  u16* xh_k = (u16*)(ws + 33554432);
  u16* xl_k = (u16*)(ws + 50331648);
  u16* xv   = (u16*)(ws + 67108864);
  u16* wqth = (u16*)(ws + 83886080);     // 2 MiB each
  u16* wqtl = (u16*)(ws + 85983232);
  u16* wkth = (u16*)(ws + 88080384);
  u16* wktl = (u16*)(ws + 90177536);
  u16* wvt  = (u16*)(ws + 92274688);
  u16* wot  = (u16*)(ws + 94371840);
  u16* qh   = (u16*)(ws + 96468992);     // 16 MiB each
  u16* ql   = (u16*)(ws + 113246208);
  u16* kh   = (u16*)(ws + 130023424);    // 64*1056*128*2 = 16.5 MiB each
  u16* kl   = (u16*)(ws + 147324928);
  u16* vt   = (u16*)(ws + 33554432);     // alias xh_k/xl_k (dead after K-proj)
  u16* obuf = (u16*)(ws + 0);            // alias xh_q (dead after Q-proj)
  u32* mbits = (u32*)(ws + 67108864);    // alias xv (dead after V-proj), 8.65 MiB
  float* invl = (float*)(ws + 164626432);

  float* out = (float*)d_out;
  float* att = out + 8388608;

  // 1. input splits / converts
  split_kernel<<<2048, 256, 0, stream>>>(queries, xh_q, xl_q, 2097152);
  split_kernel<<<2048, 256, 0, stream>>>(keys, xh_k, xl_k, 2097152);
  cvt_kernel<<<2048, 256, 0, stream>>>(values, xv, 2097152);
  // 2. weight transposes (LDS-tiled)
  wtrans_split_kernel<<<256, 256, 0, stream>>>(Wq, wqth, wqtl);
  wtrans_split_kernel<<<256, 256, 0, stream>>>(Wk, wkth, wktl);
  wtrans_cvt_kernel<<<256, 256, 0, stream>>>(Wv, wvt);
  wtrans_cvt_kernel<<<256, 256, 0, stream>>>(Wo, wot);
  // 3. projections
  gemm_kernel<true, EPI_QSPLIT><<<512, 256, 0, stream>>>(xh_q, xl_q, wqth, wqtl, bq, qh, ql, nullptr);
  gemm_kernel<true, EPI_KSPLIT><<<512, 256, 0, stream>>>(xh_k, xl_k, wkth, wktl, bk, kh, kl, nullptr);
  gemm_kernel<false, EPI_VT><<<512, 256, 0, stream>>>(xv, nullptr, wvt, nullptr, bv, vt, nullptr, nullptr);
  // 4. mask bit-pack (mbits aliases xv -- must run after V-proj)
  maskbits_kernel<<<2048, 256, 0, stream>>>(mask, mbits);
  maskfill_kernel<<<256, 256, 0, stream>>>(mbits);
  // 5. memory slots (K rows 1024..1055, V^T keys 1024..1055)
  mk_fill_kernel<<<1024, 256, 0, stream>>>(m_k, kh, kl);
  mv_fill_kernel<<<1024, 256, 0, stream>>>(m_v, vt);
  // 6. attention (unnormalized e to att, normalized O to obuf, 1/l to invl)
  attn_kernel<<<512, 512, 0, stream>>>(qh, ql, kh, kl, vt, mbits, att, obuf, invl);
  // 7. normalize att in place
  rescale_kernel<<<4096, 256, 0, stream>>>(att, invl);
  // 8. output projection
  gemm_kernel<false, EPI_OUT><<<512, 256, 0, stream>>>(obuf, nullptr, wot, nullptr, bo, nullptr, nullptr, out);
}

// Round 6
// 528.782 us; speedup vs baseline: 1.6154x; 1.1435x over previous
//
#include <hip/hip_runtime.h>

// ---------------------------------------------------------------------------
// AugmentedMemoryScaledDotProductAttention on MI355X (gfx950)
// B=8 H=8 NQ=NK=1024 D_MODEL=1024 DK=DV=128 M=16  (NKM=1040, padded to 1056)
//
// R5: full fp16 pipeline (fp16 half-ulp 2^-11 -> logit err ~0.002, 10x under
// threshold; e'=exp(s-4) keeps P in fp16 range). Single-MFMA GEMMs (no more
// bf16 hi/lo split). attn normalizes att in-kernel from L2 (rescale kernel
// deleted). 1024 blocks x 256 threads, bh-per-XCD swizzle.
// ---------------------------------------------------------------------------

typedef unsigned short u16;
typedef unsigned int   u32;
typedef _Float16 f16x8 __attribute__((ext_vector_type(8)));
typedef short    s16x8 __attribute__((ext_vector_type(8)));
typedef float    f32x4 __attribute__((ext_vector_type(4)));

#define MFMA_F16(a, b, c) __builtin_amdgcn_mfma_f32_16x16x32_f16((a), (b), (c), 0, 0, 0)

#define NQS    1024
#define NKM    1040      // NK + M
#define KSP    1056      // padded key stride
#define SCALE_QK 0.088388347648318447f   // 1/sqrt(128)
#define EXP_SHIFT 4.0f

__device__ __forceinline__ u16 f2h(float f) {
  _Float16 h = (_Float16)f;
  return __builtin_bit_cast(u16, h);
}
__device__ __forceinline__ f16x8 ld_h8(const u16* p) {
  s16x8 r = *(const s16x8*)p;
  return __builtin_bit_cast(f16x8, r);
}

// ---------------------------------------------------------------- elementwise
__global__ void cvt16_kernel(const float* __restrict__ in, u16* __restrict__ out, int n4) {
  for (int i = blockIdx.x * blockDim.x + threadIdx.x; i < n4;
       i += gridDim.x * blockDim.x) {
    float4 v = ((const float4*)in)[i];
    ushort4 h;
    h.x = f2h(v.x); h.y = f2h(v.y); h.z = f2h(v.z); h.w = f2h(v.w);
    ((ushort4*)out)[i] = h;
  }
}

// LDS-tiled transpose: W (in=1024, out=1024) rm -> t16 (out, in) rm, fp16.
__global__ __launch_bounds__(256)
void wtrans16_kernel(const float* __restrict__ w, u16* __restrict__ t16) {
  __shared__ float t[64][65];
  const int bx = blockIdx.x & 15;    // input-row (i) tile
  const int by = blockIdx.x >> 4;    // output-row (o) tile
  const int r = threadIdx.x >> 4, c4 = threadIdx.x & 15;
#pragma unroll
  for (int i = 0; i < 4; ++i) {
    const int row = bx * 64 + r + i * 16;
    float4 v = *(const float4*)&w[row * 1024 + by * 64 + c4 * 4];
    t[r + i * 16][c4 * 4 + 0] = v.x;
    t[r + i * 16][c4 * 4 + 1] = v.y;
    t[r + i * 16][c4 * 4 + 2] = v.z;
    t[r + i * 16][c4 * 4 + 3] = v.w;
  }
  __syncthreads();
  const int l = threadIdx.x & 63, og = threadIdx.x >> 6;
#pragma unroll
  for (int j = 0; j < 16; ++j) {
    const int o_local = og + j * 4;
    t16[(by * 64 + o_local) * 1024 + bx * 64 + l] = f2h(t[l][o_local]);
  }
}

// memory-slot rows of K (keys 1024..1039 = sqrt(DK)*m_k ; 1040..1055 = 0)
__global__ void mk_fill_kernel(const float* __restrict__ m_k, u16* __restrict__ kh) {
  int idx = blockIdx.x * 256 + threadIdx.x;     // B*H*32*128 = 262144
  int b = idx >> 15, h = (idx >> 12) & 7, ko = (idx >> 7) & 31, dk = idx & 127;
  float v = 0.f;
  if (ko < 16) v = 11.313708498984760f * m_k[ko * 1024 + h * 128 + dk];
  kh[((b * 8 + h) * KSP + 1024 + ko) * 128 + dk] = f2h(v);
}

// memory-slot keys of V^T (keys 1024..1039 = sqrt(M)*m_v ; 1040..1055 = 0)
__global__ void mv_fill_kernel(const float* __restrict__ m_v, u16* __restrict__ vt) {
  int idx = blockIdx.x * 256 + threadIdx.x;     // B*H*128*32 = 262144
  int b = idx >> 15, h = (idx >> 12) & 7, dv = (idx >> 5) & 127, ko = idx & 31;
  float v = (ko < 16) ? 4.0f * m_v[ko * 1024 + h * 128 + dv] : 0.f;
  vt[((b * 8 + h) * 128 + dv) * KSP + 1024 + ko] = f2h(v);
}

// mask (int32, !=0 means masked/dead) -> bit words. mbits[(bh*1024+q)*33 + w]
__global__ void maskbits_kernel(const int* __restrict__ mask, u32* __restrict__ mbits) {
  const int lane = threadIdx.x & 63;
  const int nwave = (gridDim.x * blockDim.x) >> 6;
  int wid = (blockIdx.x * blockDim.x + threadIdx.x) >> 6;
  for (int i = wid; i < 1048576; i += nwave) {        // 2^20 groups of 64 keys
    int m = mask[i * 64 + lane];
    unsigned long long bal = __ballot(m != 0);
    int row = i >> 4;                                  // (bh*1024+q)
    int col = (i * 2) & 31;
    if (lane == 0) mbits[row * 33 + col] = (u32)bal;
    else if (lane == 32) mbits[row * 33 + col + 1] = (u32)(bal >> 32);
  }
}

// word 32 of each row: keys 1024..1039 alive, 1040..1055 dead
__global__ void maskfill_kernel(u32* __restrict__ mbits) {
  int idx = blockIdx.x * 256 + threadIdx.x;   // 65536
  mbits[idx * 33 + 32] = 0xFFFF0000u;
}

// ---------------------------------------------------------------------- GEMM
// C(8192x1024) = A(8192x1024) @ B^T, B given as (1024 n-rows x 1024 k) rm.
// 128x128 tile, BK=64, 4 waves (2x2), 4x4 16x16x32 fp16 fragments per wave.
__device__ __forceinline__ void stage_tile(const u16* __restrict__ gbase,
                                           u16* sbase, int w, int lane) {
#pragma unroll
  for (int i = 0; i < 4; ++i) {
    const u16* src = gbase + (w * 32 + i * 8 + (lane >> 3)) * 1024 + (lane & 7) * 8;
    u16* dst = sbase + (w * 32 + i * 8) * 64;
    __builtin_amdgcn_global_load_lds(
        (const __attribute__((address_space(1))) void*)src,
        (__attribute__((address_space(3))) void*)dst, 16, 0, 0);
  }
}

enum { EPI_Q16 = 0, EPI_K16 = 1, EPI_VT = 2, EPI_OUT = 3 };

template <int EPI>
__global__ __launch_bounds__(256)
void gemm_kernel(const u16* __restrict__ A, const u16* __restrict__ B,
                 const float* __restrict__ bias,
                 u16* __restrict__ oH, float* __restrict__ oF) {
  __shared__ u16 sA[128 * 64];
  __shared__ u16 sB[128 * 64];
  const int lane = threadIdx.x & 63, w = threadIdx.x >> 6;
  const int bm = blockIdx.x & 63, bn = blockIdx.x >> 6;
  const int wr = w >> 1, wc = w & 1;

  f32x4 acc[4][4];
  const f32x4 fz = {0.f, 0.f, 0.f, 0.f};
#pragma unroll
  for (int m = 0; m < 4; ++m)
#pragma unroll
    for (int n = 0; n < 4; ++n) acc[m][n] = fz;

  for (int kt = 0; kt < 16; ++kt) {
    const int kb = kt * 64;
    stage_tile(A + bm * 128 * 1024 + kb, sA, w, lane);
    stage_tile(B + bn * 128 * 1024 + kb, sB, w, lane);
    __syncthreads();
    const int ro = lane & 15;
#pragma unroll
    for (int kk = 0; kk < 2; ++kk) {
      const int co = kk * 32 + (lane >> 4) * 8;
      f16x8 a[4], b[4];
#pragma unroll
      for (int m = 0; m < 4; ++m) a[m] = ld_h8(&sA[(wr * 64 + m * 16 + ro) * 64 + co]);
#pragma unroll
      for (int n = 0; n < 4; ++n) b[n] = ld_h8(&sB[(wc * 64 + n * 16 + ro) * 64 + co]);
#pragma unroll
      for (int m = 0; m < 4; ++m)
#pragma unroll
        for (int n = 0; n < 4; ++n)
          acc[m][n] = MFMA_F16(a[m], b[n], acc[m][n]);
    }
    __syncthreads();
  }

  // epilogue
#pragma unroll
  for (int m = 0; m < 4; ++m)
#pragma unroll
    for (int n = 0; n < 4; ++n) {
      const int row0 = bm * 128 + wr * 64 + m * 16 + ((lane >> 4) << 2);
      const int col = bn * 128 + wc * 64 + n * 16 + (lane & 15);
      const float bv = bias[col];
#pragma unroll
      for (int r = 0; r < 4; ++r) {
        const float y = acc[m][n][r] + bv;
        const int row = row0 + r;
        if constexpr (EPI == EPI_Q16) {
          oH[row * 1024 + col] = f2h(y);
        } else if constexpr (EPI == EPI_K16) {
          const int b = row >> 10, key = row & 1023;
          oH[((b * 8 + (col >> 7)) * KSP + key) * 128 + (col & 127)] = f2h(y);
        } else if constexpr (EPI == EPI_VT) {
          const int b = row >> 10, key = row & 1023;
          oH[((b * 8 + (col >> 7)) * 128 + (col & 127)) * KSP + key] = f2h(y);
        } else {
          oF[row * 1024 + col] = y;
        }
      }
    }
}

// ----------------------------------------------------------------- attention
// 4 waves / block (256 thr), 16 q-rows/wave -> 64 q-rows/block; 1024 blocks
// (64 bh x 16 qblk, bh-per-XCD swizzle). 33 chunks of 32 keys, T14 reg-staged
// K/V, XOR-swizzled K LDS. e'=exp(s-4) -> f32 att (unnorm) + lsum; after the
// loop each block re-reads its 64x1040 slice from L2 and normalizes in place.
__global__ __launch_bounds__(256, 4)
void attn_kernel(const u16* __restrict__ qh, const u16* __restrict__ kh,
                 const u16* __restrict__ vt, const u32* __restrict__ mbits,
                 float* __restrict__ att, u16* __restrict__ obuf) {
  __shared__ __align__(16) u16 sKh[32 * 128];
  __shared__ __align__(16) u16 sVt[128 * 40];
  __shared__ __align__(16) float sAtt[4][16][36];
  __shared__ float sInv[64];
  const int tid = threadIdx.x;
  const int lane = tid & 63, w = tid >> 6;

  // XCD swizzle: XCD x owns bh in [x*8, x*8+8), 16 qblks each.
  const int d = blockIdx.x;                  // 1024 blocks
  const int j = d >> 3;
  const int bh = (d & 7) * 8 + (j >> 4);
  const int qblk = j & 15;
  const int h = bh & 7;
  const int b = bh >> 3;
  const int qrow0 = qblk * 64 + w * 16;       // within NQ
  const int grow0 = b * NQS + qrow0;          // row in (8192 x 1024) Q/O buffers
  const int ro = lane & 15, go = lane >> 4;

  // Q fragments (held for whole kernel)
  f16x8 qf[4];
#pragma unroll
  for (int kk = 0; kk < 4; ++kk)
    qf[kk] = ld_h8(&qh[(grow0 + ro) * 1024 + h * 128 + kk * 32 + go * 8]);

  const u16* khb = kh + (size_t)bh * KSP * 128;
  const u16* vtb = vt + (size_t)bh * 128 * KSP;
  const u32* mbb = mbits + (size_t)bh * NQS * 33;
  float* attb = att + (size_t)(bh * NQS + qrow0) * NKM;

  // staging geometry: K 32 rows x 256B = 512 x 16B chunks / 256 thr = 2 each
  const int r_k  = tid >> 4;               // 0..15 (p=0) / +16 (p=1)
  const int cb_k = (tid & 15) * 16;        // byte col in 256B row
  const u16* kp0 = khb + r_k * 128 + (cb_k >> 1);
  const int dk0 = r_k * 256 + (cb_k ^ ((r_k & 7) << 4));   // same xor for row+16
  // V: 640 16B chunks (128 rows x 5); rows of 80B (64B data + 16B pad)
  int vr[3], vcs[3];
  bool vok[3];
#pragma unroll
  for (int p = 0; p < 3; ++p) {
    const int t = p * 256 + tid;
    vok[p] = (t < 640);
    const int rr = vok[p] ? (t / 5) : 0;
    const int m5 = t - rr * 5;
    vr[p] = rr;
    vcs[p] = (m5 == 4 || !vok[p]) ? 0 : m5 * 8;   // u16 col (pad -> dummy)
  }

  const f32x4 fz = {0.f, 0.f, 0.f, 0.f};
  f32x4 oacc[8];
#pragma unroll
  for (int n = 0; n < 8; ++n) oacc[n] = fz;
  float lsum[4] = {0.f, 0.f, 0.f, 0.f};

  // prologue: issue chunk-0 loads into regs
  s16x8 rkh0, rkh1, rv0, rv1, rv2;
  rkh0 = *(const s16x8*)(kp0);
  rkh1 = *(const s16x8*)(kp0 + 16 * 128);
  rv0 = *(const s16x8*)(vtb + (size_t)vr[0] * KSP + vcs[0]);
  rv1 = *(const s16x8*)(vtb + (size_t)vr[1] * KSP + vcs[1]);
  if (vok[2]) rv2 = *(const s16x8*)(vtb + (size_t)vr[2] * KSP + vcs[2]);

  for (int c = 0; c < 33; ++c) {
    const int kb = c * 32;
    __syncthreads();                       // LDS of chunk c-1 fully consumed
    *(s16x8*)((char*)sKh + dk0)        = rkh0;
    *(s16x8*)((char*)sKh + dk0 + 4096) = rkh1;
    *(s16x8*)((char*)sVt + tid * 16)         = rv0;
    *(s16x8*)((char*)sVt + (256 + tid) * 16) = rv1;
    if (vok[2]) *(s16x8*)((char*)sVt + (512 + tid) * 16) = rv2;
    if (c < 32) {                          // issue next chunk's loads
      const int nkb = (c + 1) * 32;
      rkh0 = *(const s16x8*)(kp0 + nkb * 128);
      rkh1 = *(const s16x8*)(kp0 + (nkb + 16) * 128);
      rv0 = *(const s16x8*)(vtb + (size_t)vr[0] * KSP + nkb + vcs[0]);
      rv1 = *(const s16x8*)(vtb + (size_t)vr[1] * KSP + nkb + vcs[1]);
      if (vok[2]) rv2 = *(const s16x8*)(vtb + (size_t)vr[2] * KSP + nkb + vcs[2]);
    }
    __syncthreads();                       // LDS chunk c ready

    u32 mw[4];
#pragma unroll
    for (int r = 0; r < 4; ++r) mw[r] = mbb[(qrow0 + (go << 2) + r) * 33 + c];

#pragma unroll
    for (int t = 0; t < 2; ++t) {
      f32x4 s = fz;
      const int rr = t * 16 + ro;                  // key row in chunk
      const int sw = (rr & 7) << 4;
      __builtin_amdgcn_s_setprio(1);
#pragma unroll
      for (int kk = 0; kk < 4; ++kk) {
        const int off = rr * 256 + ((kk * 64 + go * 16) ^ sw);
        f16x8 bhf = ld_h8((const u16*)((const char*)sKh + off));
        s = MFMA_F16(qf[kk], bhf, s);
      }
      __builtin_amdgcn_s_setprio(0);
      const int key_in = t * 16 + ro;
#pragma unroll
      for (int r = 0; r < 4; ++r) {
        const int lrow = (go << 2) + r;
        const float sv = s[r] * SCALE_QK - EXP_SHIFT;
        const bool dead = (mw[r] >> key_in) & 1;
        const float e = dead ? 0.f : __expf(sv);
        lsum[r] += e;
        sAtt[w][lrow][t * 16 + ro] = e;
      }
    }

    // att writeout (unnormalized e'): 4 lanes cover one row's 32 f32 (128B)
    {
      const int arow = lane >> 2, cg = lane & 3;
      if (kb + cg * 8 < NKM) {
        f32x4 v0 = *(const f32x4*)&sAtt[w][arow][cg * 8];
        f32x4 v1 = *(const f32x4*)&sAtt[w][arow][cg * 8 + 4];
        float* dst = attb + (size_t)arow * NKM + kb + cg * 8;
        *(f32x4*)dst = v0;
        *(f32x4*)(dst + 4) = v1;
      }
    }

    // PV: A fragment (rows=q, cols=key) from sAtt (cvt fp16), B from sVt
    {
      f32x4 p0 = *(const f32x4*)&sAtt[w][ro][go * 8];
      f32x4 p1 = *(const f32x4*)&sAtt[w][ro][go * 8 + 4];
      f16x8 pa;
      pa[0] = (_Float16)p0[0]; pa[1] = (_Float16)p0[1];
      pa[2] = (_Float16)p0[2]; pa[3] = (_Float16)p0[3];
      pa[4] = (_Float16)p1[0]; pa[5] = (_Float16)p1[1];
      pa[6] = (_Float16)p1[2]; pa[7] = (_Float16)p1[3];
      __builtin_amdgcn_s_setprio(1);
#pragma unroll
      for (int n = 0; n < 8; ++n) {
        f16x8 vb = ld_h8((const u16*)((const char*)sVt + (n * 16 + ro) * 80 + go * 16));
        oacc[n] = MFMA_F16(pa, vb, oacc[n]);
      }
      __builtin_amdgcn_s_setprio(0);
    }
  }

  // row sums: reduce across the 16 lanes of each group
#pragma unroll
  for (int r = 0; r < 4; ++r) {
    lsum[r] += __shfl_xor(lsum[r], 1);
    lsum[r] += __shfl_xor(lsum[r], 2);
    lsum[r] += __shfl_xor(lsum[r], 4);
    lsum[r] += __shfl_xor(lsum[r], 8);
  }
  float inv[4];
#pragma unroll
  for (int r = 0; r < 4; ++r) inv[r] = 1.0f / lsum[r];
  if (ro == 0) {
#pragma unroll
    for (int r = 0; r < 4; ++r)
      sInv[w * 16 + (go << 2) + r] = inv[r];
  }
  // write O = oacc / l  (fp16, row = b*NQ+q, col = h*128+dv)
#pragma unroll
  for (int n = 0; n < 8; ++n)
#pragma unroll
    for (int r = 0; r < 4; ++r) {
      const float o = oacc[n][r] * inv[r];
      obuf[(grow0 + (go << 2) + r) * 1024 + h * 128 + n * 16 + ro] = f2h(o);
    }

  // normalize this block's 64x1040 att slice in place (reads hit L2)
  __syncthreads();   // drains vmcnt(0): all unnormalized stores visible
  {
    float* attblk = att + (size_t)(bh * NQS + qblk * 64) * NKM;
    const int row = tid >> 2, part = tid & 3;
    const float iv = sInv[row];
    float* rp = attblk + (size_t)row * NKM;
#pragma unroll 5
    for (int k = 0; k < 65; ++k) {
      float* p = rp + (part + 4 * k) * 4;
      f32x4 v = *(const f32x4*)p;
      v[0] *= iv; v[1] *= iv; v[2] *= iv; v[3] *= iv;
      *(f32x4*)p = v;
    }
  }
}

// --------------------------------------------------------------------- launch
extern "C" void kernel_launch(void* const* d_in, const int* in_sizes, int n_in,
                              void* d_out, int out_size, void* d_ws, size_t ws_size,
                              hipStream_t stream) {
  const float* queries = (const float*)d_in[0];
  const float* keys    = (const float*)d_in[1];
  const float* values  = (const float*)d_in[2];
  const int*   mask    = (const int*)d_in[3];
  const float* Wq = (const float*)d_in[4];
  const float* bq = (const float*)d_in[5];
  const float* Wk = (const float*)d_in[6];
  const float* bk = (const float*)d_in[7];
  const float* Wv = (const float*)d_in[8];
  const float* bv = (const float*)d_in[9];
  const float* Wo = (const float*)d_in[10];
  const float* bo = (const float*)d_in[11];
  const float* m_k = (const float*)d_in[12];
  const float* m_v = (const float*)d_in[13];

  if (ws_size < 135528448) return;   // layout below needs ~129.3 MiB

  char* ws = (char*)d_ws;
  u16* xq  = (u16*)(ws + 0);           // 16 MiB
  u16* xk  = (u16*)(ws + 16777216);    // 16 MiB
  u16* xv  = (u16*)(ws + 33554432);    // 16 MiB
  u16* wq  = (u16*)(ws + 50331648);    // 2 MiB
  u16* wk  = (u16*)(ws + 52428800);
  u16* wv  = (u16*)(ws + 54525952);
  u16* wo  = (u16*)(ws + 56623104);
  u16* q16 = (u16*)(ws + 58720256);    // 16 MiB
  u16* k16 = (u16*)(ws + 75497472);    // 64*1056*128*2 = 16.5 MiB
  u16* vt  = (u16*)(ws + 92798976);    // 16.5 MiB
  u16* obuf= (u16*)(ws + 110100480);   // 16 MiB
  u32* mbits=(u32*)(ws + 126877696);   // 8.65 MiB

  float* out = (float*)d_out;
  float* att = out + 8388608;

  // 1. input converts (f32 -> fp16)
  cvt16_kernel<<<2048, 256, 0, stream>>>(queries, xq, 2097152);
  cvt16_kernel<<<2048, 256, 0, stream>>>(keys,    xk, 2097152);
  cvt16_kernel<<<2048, 256, 0, stream>>>(values,  xv, 2097152);
  // 2. weight transposes (LDS-tiled, fp16)
  wtrans16_kernel<<<256, 256, 0, stream>>>(Wq, wq);
  wtrans16_kernel<<<256, 256, 0, stream>>>(Wk, wk);
  wtrans16_kernel<<<256, 256, 0, stream>>>(Wv, wv);
  wtrans16_kernel<<<256, 256, 0, stream>>>(Wo, wo);
  // 3. projections (plain fp16 GEMMs)
  gemm_kernel<EPI_Q16><<<512, 256, 0, stream>>>(xq, wq, bq, q16, nullptr);
  gemm_kernel<EPI_K16><<<512, 256, 0, stream>>>(xk, wk, bk, k16, nullptr);
  gemm_kernel<EPI_VT> <<<512, 256, 0, stream>>>(xv, wv, bv, vt,  nullptr);
  // 4. mask bit-pack
  maskbits_kernel<<<2048, 256, 0, stream>>>(mask, mbits);
  maskfill_kernel<<<256, 256, 0, stream>>>(mbits);
  // 5. memory slots
  mk_fill_kernel<<<1024, 256, 0, stream>>>(m_k, k16);
  mv_fill_kernel<<<1024, 256, 0, stream>>>(m_v, vt);
  // 6. attention (writes normalized att + O)
  attn_kernel<<<1024, 256, 0, stream>>>(q16, k16, vt, mbits, att, obuf);
  // 7. output projection
  gemm_kernel<EPI_OUT><<<512, 256, 0, stream>>>(obuf, wo, bo, nullptr, out);
}

// Round 7
// 409.467 us; speedup vs baseline: 2.0861x; 1.2914x over previous
//
#include <hip/hip_runtime.h>

// ---------------------------------------------------------------------------
// AugmentedMemoryScaledDotProductAttention on MI355X (gfx950)
// B=8 H=8 NQ=NK=1024 D_MODEL=1024 DK=DV=128 M=16  (NKM=1040, padded to 1056)
//
// R6: two-pass attn -- phase 1 scans K (64-key chunks) computing row sums
// only; phase 2 recomputes QK^T (K is L2-hot) and writes NORMALIZED att
// directly + accumulates PV with normalized P (no post-divide, no re-read).
// Kills R5's +546MB normalize traffic. maskbits now int4-wide.
// fp16 pipeline throughout (logit err ~0.002 << 0.059 threshold).
// ---------------------------------------------------------------------------

typedef unsigned short u16;
typedef unsigned int   u32;
typedef _Float16 f16x8 __attribute__((ext_vector_type(8)));
typedef short    s16x8 __attribute__((ext_vector_type(8)));
typedef float    f32x4 __attribute__((ext_vector_type(4)));

#define MFMA_F16(a, b, c) __builtin_amdgcn_mfma_f32_16x16x32_f16((a), (b), (c), 0, 0, 0)

#define NQS    1024
#define NKM    1040      // NK + M
#define KSP    1056      // padded key stride
#define SCALE_QK 0.088388347648318447f   // 1/sqrt(128)

__device__ __forceinline__ u16 f2h(float f) {
  _Float16 h = (_Float16)f;
  return __builtin_bit_cast(u16, h);
}
__device__ __forceinline__ f16x8 ld_h8(const u16* p) {
  s16x8 r = *(const s16x8*)p;
  return __builtin_bit_cast(f16x8, r);
}

// ---------------------------------------------------------------- elementwise
__global__ void cvt16_kernel(const float* __restrict__ in, u16* __restrict__ out, int n4) {
  for (int i = blockIdx.x * blockDim.x + threadIdx.x; i < n4;
       i += gridDim.x * blockDim.x) {
    float4 v = ((const float4*)in)[i];
    ushort4 h;
    h.x = f2h(v.x); h.y = f2h(v.y); h.z = f2h(v.z); h.w = f2h(v.w);
    ((ushort4*)out)[i] = h;
  }
}

// LDS-tiled transpose: W (in=1024, out=1024) rm -> t16 (out, in) rm, fp16.
__global__ __launch_bounds__(256)
void wtrans16_kernel(const float* __restrict__ w, u16* __restrict__ t16) {
  __shared__ float t[64][65];
  const int bx = blockIdx.x & 15;    // input-row (i) tile
  const int by = blockIdx.x >> 4;    // output-row (o) tile
  const int r = threadIdx.x >> 4, c4 = threadIdx.x & 15;
#pragma unroll
  for (int i = 0; i < 4; ++i) {
    const int row = bx * 64 + r + i * 16;
    float4 v = *(const float4*)&w[row * 1024 + by * 64 + c4 * 4];
    t[r + i * 16][c4 * 4 + 0] = v.x;
    t[r + i * 16][c4 * 4 + 1] = v.y;
    t[r + i * 16][c4 * 4 + 2] = v.z;
    t[r + i * 16][c4 * 4 + 3] = v.w;
  }
  __syncthreads();
  const int l = threadIdx.x & 63, og = threadIdx.x >> 6;
#pragma unroll
  for (int j = 0; j < 16; ++j) {
    const int o_local = og + j * 4;
    t16[(by * 64 + o_local) * 1024 + bx * 64 + l] = f2h(t[l][o_local]);
  }
}

// memory-slot rows of K (keys 1024..1039 = sqrt(DK)*m_k ; 1040..1055 = 0)
__global__ void mk_fill_kernel(const float* __restrict__ m_k, u16* __restrict__ kh) {
  int idx = blockIdx.x * 256 + threadIdx.x;     // B*H*32*128 = 262144
  int b = idx >> 15, h = (idx >> 12) & 7, ko = (idx >> 7) & 31, dk = idx & 127;
  float v = 0.f;
  if (ko < 16) v = 11.313708498984760f * m_k[ko * 1024 + h * 128 + dk];
  kh[((b * 8 + h) * KSP + 1024 + ko) * 128 + dk] = f2h(v);
}

// memory-slot keys of V^T (keys 1024..1039 = sqrt(M)*m_v ; 1040..1055 = 0)
__global__ void mv_fill_kernel(const float* __restrict__ m_v, u16* __restrict__ vt) {
  int idx = blockIdx.x * 256 + threadIdx.x;     // B*H*128*32 = 262144
  int b = idx >> 15, h = (idx >> 12) & 7, dv = (idx >> 5) & 127, ko = idx & 31;
  float v = (ko < 16) ? 4.0f * m_v[ko * 1024 + h * 128 + dv] : 0.f;
  vt[((b * 8 + h) * 128 + dv) * KSP + 1024 + ko] = f2h(v);
}

// mask (int32, !=0 dead) -> bit words. mbits[(bh*1024+q)*33 + w].
// int4 loads: each lane covers 4 keys; 8-lane shuffle-OR assembles one u32.
__global__ void maskbits_kernel(const int* __restrict__ mask, u32* __restrict__ mbits) {
  const int lane = threadIdx.x & 63;
  const int nwave = (gridDim.x * blockDim.x) >> 6;
  int wid = (blockIdx.x * blockDim.x + threadIdx.x) >> 6;
  for (int g = wid; g < 262144; g += nwave) {       // 256-key groups
    const int4 m = *(const int4*)&mask[(size_t)g * 256 + lane * 4];
    u32 nib = (m.x ? 1u : 0u) | (m.y ? 2u : 0u) | (m.z ? 4u : 0u) | (m.w ? 8u : 0u);
    u32 v = nib << ((lane & 7) * 4);
    v |= __shfl_xor(v, 1);
    v |= __shfl_xor(v, 2);
    v |= __shfl_xor(v, 4);
    if ((lane & 7) == 0) {
      const int row = g >> 2;                        // (bh*1024+q)
      const int word = ((g & 3) << 3) + (lane >> 3); // 0..31
      mbits[row * 33 + word] = v;
    }
  }
}

// word 32 of each row: keys 1024..1039 alive, 1040..1055 dead
__global__ void maskfill_kernel(u32* __restrict__ mbits) {
  int idx = blockIdx.x * 256 + threadIdx.x;   // 65536
  mbits[idx * 33 + 32] = 0xFFFF0000u;
}

// ---------------------------------------------------------------------- GEMM
// C(8192x1024) = A(8192x1024) @ B^T, B given as (1024 n-rows x 1024 k) rm.
// 128x128 tile, BK=64, 4 waves (2x2), 4x4 16x16x32 fp16 fragments per wave.
__device__ __forceinline__ void stage_tile(const u16* __restrict__ gbase,
                                           u16* sbase, int w, int lane) {
#pragma unroll
  for (int i = 0; i < 4; ++i) {
    const u16* src = gbase + (w * 32 + i * 8 + (lane >> 3)) * 1024 + (lane & 7) * 8;
    u16* dst = sbase + (w * 32 + i * 8) * 64;
    __builtin_amdgcn_global_load_lds(
        (const __attribute__((address_space(1))) void*)src,
        (__attribute__((address_space(3))) void*)dst, 16, 0, 0);
  }
}

enum { EPI_Q16 = 0, EPI_K16 = 1, EPI_VT = 2, EPI_OUT = 3 };

template <int EPI>
__global__ __launch_bounds__(256)
void gemm_kernel(const u16* __restrict__ A, const u16* __restrict__ B,
                 const float* __restrict__ bias,
                 u16* __restrict__ oH, float* __restrict__ oF) {
  __shared__ u16 sA[128 * 64];
  __shared__ u16 sB[128 * 64];
  const int lane = threadIdx.x & 63, w = threadIdx.x >> 6;
  const int bm = blockIdx.x & 63, bn = blockIdx.x >> 6;
  const int wr = w >> 1, wc = w & 1;

  f32x4 acc[4][4];
  const f32x4 fz = {0.f, 0.f, 0.f, 0.f};
#pragma unroll
  for (int m = 0; m < 4; ++m)
#pragma unroll
    for (int n = 0; n < 4; ++n) acc[m][n] = fz;

  for (int kt = 0; kt < 16; ++kt) {
    const int kb = kt * 64;
    stage_tile(A + bm * 128 * 1024 + kb, sA, w, lane);
    stage_tile(B + bn * 128 * 1024 + kb, sB, w, lane);
    __syncthreads();
    const int ro = lane & 15;
#pragma unroll
    for (int kk = 0; kk < 2; ++kk) {
      const int co = kk * 32 + (lane >> 4) * 8;
      f16x8 a[4], b[4];
#pragma unroll
      for (int m = 0; m < 4; ++m) a[m] = ld_h8(&sA[(wr * 64 + m * 16 + ro) * 64 + co]);
#pragma unroll
      for (int n = 0; n < 4; ++n) b[n] = ld_h8(&sB[(wc * 64 + n * 16 + ro) * 64 + co]);
#pragma unroll
      for (int m = 0; m < 4; ++m)
#pragma unroll
        for (int n = 0; n < 4; ++n)
          acc[m][n] = MFMA_F16(a[m], b[n], acc[m][n]);
    }
    __syncthreads();
  }

  // epilogue
#pragma unroll
  for (int m = 0; m < 4; ++m)
#pragma unroll
    for (int n = 0; n < 4; ++n) {
      const int row0 = bm * 128 + wr * 64 + m * 16 + ((lane >> 4) << 2);
      const int col = bn * 128 + wc * 64 + n * 16 + (lane & 15);
      const float bv = bias[col];
#pragma unroll
      for (int r = 0; r < 4; ++r) {
        const float y = acc[m][n][r] + bv;
        const int row = row0 + r;
        if constexpr (EPI == EPI_Q16) {
          oH[row * 1024 + col] = f2h(y);
        } else if constexpr (EPI == EPI_K16) {
          const int b = row >> 10, key = row & 1023;
          oH[((b * 8 + (col >> 7)) * KSP + key) * 128 + (col & 127)] = f2h(y);
        } else if constexpr (EPI == EPI_VT) {
          const int b = row >> 10, key = row & 1023;
          oH[((b * 8 + (col >> 7)) * 128 + (col & 127)) * KSP + key] = f2h(y);
        } else {
          oF[row * 1024 + col] = y;
        }
      }
    }
}

// ----------------------------------------------------------------- attention
// 4 waves/block, 16 q-rows/wave, 1024 blocks (64 bh x 16 qblk, bh-per-XCD).
// Phase 1: 16x64-key + 1x32-key chunks, QK^T+exp -> lsum only (no stores).
// Shuffle-reduce -> inv[4] in registers. Phase 2: 33x32-key chunks, QK^T
// recomputed (K L2-hot), e*inv -> normalized att write + PV (p normalized,
// no post-divide). T14 reg-staging, XOR-swizzled K LDS throughout.
__global__ __launch_bounds__(256, 4)
void attn_kernel(const u16* __restrict__ qh, const u16* __restrict__ kh,
                 const u16* __restrict__ vt, const u32* __restrict__ mbits,
                 float* __restrict__ att, u16* __restrict__ obuf) {
  __shared__ __align__(16) u16 sK[64 * 128];        // 16 KB (ph1 64 keys; ph2 first 8 KB)
  __shared__ __align__(16) u16 sVt[128 * 40];       // 10 KB (ph2)
  __shared__ __align__(16) float sAtt[4][16][36];   // 9 KB
  const int tid = threadIdx.x;
  const int lane = tid & 63, w = tid >> 6;

  // XCD swizzle: XCD x owns bh in [x*8, x*8+8), 16 qblks each.
  const int d = blockIdx.x;                  // 1024 blocks
  const int j = d >> 3;
  const int bh = (d & 7) * 8 + (j >> 4);
  const int qblk = j & 15;
  const int h = bh & 7;
  const int b = bh >> 3;
  const int qrow0 = qblk * 64 + w * 16;       // within NQ
  const int grow0 = b * NQS + qrow0;          // row in (8192 x 1024) Q/O buffers
  const int ro = lane & 15, go = lane >> 4;

  // Q fragments (held for whole kernel)
  f16x8 qf[4];
#pragma unroll
  for (int kk = 0; kk < 4; ++kk)
    qf[kk] = ld_h8(&qh[(grow0 + ro) * 1024 + h * 128 + kk * 32 + go * 8]);

  const u16* khb = kh + (size_t)bh * KSP * 128;
  const u16* vtb = vt + (size_t)bh * 128 * KSP;
  const u32* mbb = mbits + (size_t)bh * NQS * 33;
  float* attb = att + (size_t)(bh * NQS + qrow0) * NKM;

  // K staging geometry: thread -> row r_k (+16/+32/+48), 16B col
  const int r_k  = tid >> 4;               // 0..15
  const int cb_k = (tid & 15) * 16;        // byte col in 256B row
  const u16* kp0 = khb + r_k * 128 + (cb_k >> 1);
  const int dk0 = r_k * 256 + (cb_k ^ ((r_k & 7) << 4));   // xor invariant to +16 rows

  const f32x4 fz = {0.f, 0.f, 0.f, 0.f};
  float lsum[4] = {0.f, 0.f, 0.f, 0.f};

  // ================= phase 1: row sums (64-key chunks + 32-key tail) ======
  {
    s16x8 ra = *(const s16x8*)(kp0);
    s16x8 rb = *(const s16x8*)(kp0 + 16 * 128);
    s16x8 rc = *(const s16x8*)(kp0 + 32 * 128);
    s16x8 rd = *(const s16x8*)(kp0 + 48 * 128);
    for (int c = 0; c < 16; ++c) {
      __syncthreads();
      *(s16x8*)((char*)sK + dk0)         = ra;
      *(s16x8*)((char*)sK + dk0 + 4096)  = rb;
      *(s16x8*)((char*)sK + dk0 + 8192)  = rc;
      *(s16x8*)((char*)sK + dk0 + 12288) = rd;
      if (c < 15) {
        const u16* p = kp0 + (c + 1) * 64 * 128;
        ra = *(const s16x8*)(p);
        rb = *(const s16x8*)(p + 16 * 128);
        rc = *(const s16x8*)(p + 32 * 128);
        rd = *(const s16x8*)(p + 48 * 128);
      } else {                    // prefetch the 32-key memory tail
        ra = *(const s16x8*)(kp0 + 1024 * 128);
        rb = *(const s16x8*)(kp0 + 1040 * 128);
      }
      __syncthreads();
      u32 mw0[4], mw1[4];
#pragma unroll
      for (int r = 0; r < 4; ++r) {
        const int row = qrow0 + (go << 2) + r;
        mw0[r] = mbb[row * 33 + 2 * c];
        mw1[r] = mbb[row * 33 + 2 * c + 1];
      }
#pragma unroll
      for (int t = 0; t < 4; ++t) {
        f32x4 s = fz;
        const int rr = t * 16 + ro;
        const int sw = (rr & 7) << 4;
        __builtin_amdgcn_s_setprio(1);
#pragma unroll
        for (int kk = 0; kk < 4; ++kk) {
          const int off = rr * 256 + ((kk * 64 + go * 16) ^ sw);
          s = MFMA_F16(qf[kk], ld_h8((const u16*)((const char*)sK + off)), s);
        }
        __builtin_amdgcn_s_setprio(0);
        const int bit = (t & 1) * 16 + ro;
#pragma unroll
        for (int r = 0; r < 4; ++r) {
          const u32 mw = (t < 2) ? mw0[r] : mw1[r];
          const bool dead = (mw >> bit) & 1;
          const float e = dead ? 0.f : __expf(s[r] * SCALE_QK);
          lsum[r] += e;
        }
      }
    }
    // 32-key tail (keys 1024..1055), staged in ra/rb
    __syncthreads();
    *(s16x8*)((char*)sK + dk0)        = ra;
    *(s16x8*)((char*)sK + dk0 + 4096) = rb;
    __syncthreads();
    u32 mwt[4];
#pragma unroll
    for (int r = 0; r < 4; ++r)
      mwt[r] = mbb[(qrow0 + (go << 2) + r) * 33 + 32];
#pragma unroll
    for (int t = 0; t < 2; ++t) {
      f32x4 s = fz;
      const int rr = t * 16 + ro;
      const int sw = (rr & 7) << 4;
#pragma unroll
      for (int kk = 0; kk < 4; ++kk) {
        const int off = rr * 256 + ((kk * 64 + go * 16) ^ sw);
        s = MFMA_F16(qf[kk], ld_h8((const u16*)((const char*)sK + off)), s);
      }
      const int bit = t * 16 + ro;
#pragma unroll
      for (int r = 0; r < 4; ++r) {
        const bool dead = (mwt[r] >> bit) & 1;
        lsum[r] += dead ? 0.f : __expf(s[r] * SCALE_QK);
      }
    }
  }

  // reduce across the 16 ro-lanes of each go-group -> every lane holds inv[]
  float inv[4];
#pragma unroll
  for (int r = 0; r < 4; ++r) {
    lsum[r] += __shfl_xor(lsum[r], 1);
    lsum[r] += __shfl_xor(lsum[r], 2);
    lsum[r] += __shfl_xor(lsum[r], 4);
    lsum[r] += __shfl_xor(lsum[r], 8);
    inv[r] = 1.0f / lsum[r];
  }

  // ================= phase 2: normalized att + PV =========================
  f32x4 oacc[8];
#pragma unroll
  for (int n = 0; n < 8; ++n) oacc[n] = fz;

  // V staging geometry: 640 16B chunks (128 rows x 5; col 4 = pad -> dummy)
  int vr[3], vcs[3];
  bool vok[3];
#pragma unroll
  for (int p = 0; p < 3; ++p) {
    const int t = p * 256 + tid;
    vok[p] = (t < 640);
    const int rr = vok[p] ? (t / 5) : 0;
    const int m5 = t - rr * 5;
    vr[p] = rr;
    vcs[p] = (m5 == 4 || !vok[p]) ? 0 : m5 * 8;
  }

  s16x8 rkh0, rkh1, rv0, rv1, rv2;
  rkh0 = *(const s16x8*)(kp0);
  rkh1 = *(const s16x8*)(kp0 + 16 * 128);
  rv0 = *(const s16x8*)(vtb + (size_t)vr[0] * KSP + vcs[0]);
  rv1 = *(const s16x8*)(vtb + (size_t)vr[1] * KSP + vcs[1]);
  if (vok[2]) rv2 = *(const s16x8*)(vtb + (size_t)vr[2] * KSP + vcs[2]);

  for (int c = 0; c < 33; ++c) {
    const int kb = c * 32;
    __syncthreads();                       // LDS of previous chunk consumed
    *(s16x8*)((char*)sK + dk0)        = rkh0;
    *(s16x8*)((char*)sK + dk0 + 4096) = rkh1;
    *(s16x8*)((char*)sVt + tid * 16)         = rv0;
    *(s16x8*)((char*)sVt + (256 + tid) * 16) = rv1;
    if (vok[2]) *(s16x8*)((char*)sVt + (512 + tid) * 16) = rv2;
    if (c < 32) {                          // issue next chunk's loads
      const int nkb = (c + 1) * 32;
      rkh0 = *(const s16x8*)(kp0 + nkb * 128);
      rkh1 = *(const s16x8*)(kp0 + (nkb + 16) * 128);
      rv0 = *(const s16x8*)(vtb + (size_t)vr[0] * KSP + nkb + vcs[0]);
      rv1 = *(const s16x8*)(vtb + (size_t)vr[1] * KSP + nkb + vcs[1]);
      if (vok[2]) rv2 = *(const s16x8*)(vtb + (size_t)vr[2] * KSP + nkb + vcs[2]);
    }
    __syncthreads();                       // LDS chunk c ready

    u32 mw[4];
#pragma unroll
    for (int r = 0; r < 4; ++r) mw[r] = mbb[(qrow0 + (go << 2) + r) * 33 + c];

#pragma unroll
    for (int t = 0; t < 2; ++t) {
      f32x4 s = fz;
      const int rr = t * 16 + ro;                  // key row in chunk
      const int sw = (rr & 7) << 4;
      __builtin_amdgcn_s_setprio(1);
#pragma unroll
      for (int kk = 0; kk < 4; ++kk) {
        const int off = rr * 256 + ((kk * 64 + go * 16) ^ sw);
        s = MFMA_F16(qf[kk], ld_h8((const u16*)((const char*)sK + off)), s);
      }
      __builtin_amdgcn_s_setprio(0);
      const int key_in = t * 16 + ro;
#pragma unroll
      for (int r = 0; r < 4; ++r) {
        const int lrow = (go << 2) + r;
        const bool dead = (mw[r] >> key_in) & 1;
        const float e = dead ? 0.f : __expf(s[r] * SCALE_QK);
        sAtt[w][lrow][t * 16 + ro] = e * inv[r];   // normalized
      }
    }

    // att writeout (normalized): 4 lanes cover one row's 32 f32 (128B)
    {
      const int arow = lane >> 2, cg = lane & 3;
      if (kb + cg * 8 < NKM) {
        f32x4 v0 = *(const f32x4*)&sAtt[w][arow][cg * 8];
        f32x4 v1 = *(const f32x4*)&sAtt[w][arow][cg * 8 + 4];
        float* dst = attb + (size_t)arow * NKM + kb + cg * 8;
        *(f32x4*)dst = v0;
        *(f32x4*)(dst + 4) = v1;
      }
    }

    // PV with normalized p (A rows=q, cols=key), B from sVt
    {
      f32x4 p0 = *(const f32x4*)&sAtt[w][ro][go * 8];
      f32x4 p1 = *(const f32x4*)&sAtt[w][ro][go * 8 + 4];
      f16x8 pa;
      pa[0] = (_Float16)p0[0]; pa[1] = (_Float16)p0[1];
      pa[2] = (_Float16)p0[2]; pa[3] = (_Float16)p0[3];
      pa[4] = (_Float16)p1[0]; pa[5] = (_Float16)p1[1];
      pa[6] = (_Float16)p1[2]; pa[7] = (_Float16)p1[3];
      __builtin_amdgcn_s_setprio(1);
#pragma unroll
      for (int n = 0; n < 8; ++n) {
        f16x8 vb = ld_h8((const u16*)((const char*)sVt + (n * 16 + ro) * 80 + go * 16));
        oacc[n] = MFMA_F16(pa, vb, oacc[n]);
      }
      __builtin_amdgcn_s_setprio(0);
    }
  }

  // write O (already normalized; fp16, row = b*NQ+q, col = h*128+dv)
#pragma unroll
  for (int n = 0; n < 8; ++n)
#pragma unroll
    for (int r = 0; r < 4; ++r)
      obuf[(grow0 + (go << 2) + r) * 1024 + h * 128 + n * 16 + ro] = f2h(oacc[n][r]);
}

// --------------------------------------------------------------------- launch
extern "C" void kernel_launch(void* const* d_in, const int* in_sizes, int n_in,
                              void* d_out, int out_size, void* d_ws, size_t ws_size,
                              hipStream_t stream) {
  const float* queries = (const float*)d_in[0];
  const float* keys    = (const float*)d_in[1];
  const float* values  = (const float*)d_in[2];
  const int*   mask    = (const int*)d_in[3];
  const float* Wq = (const float*)d_in[4];
  const float* bq = (const float*)d_in[5];
  const float* Wk = (const float*)d_in[6];
  const float* bk = (const float*)d_in[7];
  const float* Wv = (const float*)d_in[8];
  const float* bv = (const float*)d_in[9];
  const float* Wo = (const float*)d_in[10];
  const float* bo = (const float*)d_in[11];
  const float* m_k = (const float*)d_in[12];
  const float* m_v = (const float*)d_in[13];

  if (ws_size < 135528448) return;   // layout below needs ~129.3 MiB

  char* ws = (char*)d_ws;
  u16* xq  = (u16*)(ws + 0);           // 16 MiB
  u16* xk  = (u16*)(ws + 16777216);    // 16 MiB
  u16* xv  = (u16*)(ws + 33554432);    // 16 MiB
  u16* wq  = (u16*)(ws + 50331648);    // 2 MiB
  u16* wk  = (u16*)(ws + 52428800);
  u16* wv  = (u16*)(ws + 54525952);
  u16* wo  = (u16*)(ws + 56623104);
  u16* q16 = (u16*)(ws + 58720256);    // 16 MiB
  u16* k16 = (u16*)(ws + 75497472);    // 64*1056*128*2 = 16.5 MiB
  u16* vt  = (u16*)(ws + 92798976);    // 16.5 MiB
  u16* obuf= (u16*)(ws + 110100480);   // 16 MiB
  u32* mbits=(u32*)(ws + 126877696);   // 8.65 MiB

  float* out = (float*)d_out;
  float* att = out + 8388608;

  // 1. input converts (f32 -> fp16)
  cvt16_kernel<<<2048, 256, 0, stream>>>(queries, xq, 2097152);
  cvt16_kernel<<<2048, 256, 0, stream>>>(keys,    xk, 2097152);
  cvt16_kernel<<<2048, 256, 0, stream>>>(values,  xv, 2097152);
  // 2. weight transposes (LDS-tiled, fp16)
  wtrans16_kernel<<<256, 256, 0, stream>>>(Wq, wq);
  wtrans16_kernel<<<256, 256, 0, stream>>>(Wk, wk);
  wtrans16_kernel<<<256, 256, 0, stream>>>(Wv, wv);
  wtrans16_kernel<<<256, 256, 0, stream>>>(Wo, wo);
  // 3. projections (plain fp16 GEMMs)
  gemm_kernel<EPI_Q16><<<512, 256, 0, stream>>>(xq, wq, bq, q16, nullptr);
  gemm_kernel<EPI_K16><<<512, 256, 0, stream>>>(xk, wk, bk, k16, nullptr);
  gemm_kernel<EPI_VT> <<<512, 256, 0, stream>>>(xv, wv, bv, vt,  nullptr);
  // 4. mask bit-pack
  maskbits_kernel<<<2048, 256, 0, stream>>>(mask, mbits);
  maskfill_kernel<<<256, 256, 0, stream>>>(mbits);
  // 5. memory slots
  mk_fill_kernel<<<1024, 256, 0, stream>>>(m_k, k16);
  mv_fill_kernel<<<1024, 256, 0, stream>>>(m_v, vt);
  // 6. attention (normalized att + O in one kernel, two-pass over K)
  attn_kernel<<<1024, 256, 0, stream>>>(q16, k16, vt, mbits, att, obuf);
  // 7. output projection
  gemm_kernel<EPI_OUT><<<512, 256, 0, stream>>>(obuf, wo, bo, nullptr, out);
}

// Round 8
// 406.211 us; speedup vs baseline: 2.1029x; 1.0080x over previous
//
#include <hip/hip_runtime.h>

// ---------------------------------------------------------------------------
// AugmentedMemoryScaledDotProductAttention on MI355X (gfx950)
// B=8 H=8 NQ=NK=1024 D_MODEL=1024 DK=DV=128 M=16  (NKM=1040, padded to 1088)
//
// R7: key axis padded to 1088 = 17*64 -> both attn phases run 17 uniform
// 64-key chunks (phase-2 barriers 66 -> 34). V staged as 64-key tile
// (144B rows). O written via LDS re-tile (coalesced 16B stores). Mask
// bitmap 34 words/row (word 33 = all dead). fp16 pipeline throughout.
// ---------------------------------------------------------------------------

typedef unsigned short u16;
typedef unsigned int   u32;
typedef _Float16 f16x8 __attribute__((ext_vector_type(8)));
typedef short    s16x8 __attribute__((ext_vector_type(8)));
typedef float    f32x4 __attribute__((ext_vector_type(4)));

#define MFMA_F16(a, b, c) __builtin_amdgcn_mfma_f32_16x16x32_f16((a), (b), (c), 0, 0, 0)

#define NQS    1024
#define NKM    1040      // NK + M
#define KSP    1088      // padded key stride (17 * 64)
#define MW     34        // mask words per row
#define SCALE_QK 0.088388347648318447f   // 1/sqrt(128)

__device__ __forceinline__ u16 f2h(float f) {
  _Float16 h = (_Float16)f;
  return __builtin_bit_cast(u16, h);
}
__device__ __forceinline__ f16x8 ld_h8(const u16* p) {
  s16x8 r = *(const s16x8*)p;
  return __builtin_bit_cast(f16x8, r);
}

// ---------------------------------------------------------------- elementwise
__global__ void cvt16_kernel(const float* __restrict__ in, u16* __restrict__ out, int n4) {
  for (int i = blockIdx.x * blockDim.x + threadIdx.x; i < n4;
       i += gridDim.x * blockDim.x) {
    float4 v = ((const float4*)in)[i];
    ushort4 h;
    h.x = f2h(v.x); h.y = f2h(v.y); h.z = f2h(v.z); h.w = f2h(v.w);
    ((ushort4*)out)[i] = h;
  }
}

// LDS-tiled transpose: W (in=1024, out=1024) rm -> t16 (out, in) rm, fp16.
__global__ __launch_bounds__(256)
void wtrans16_kernel(const float* __restrict__ w, u16* __restrict__ t16) {
  __shared__ float t[64][65];
  const int bx = blockIdx.x & 15;    // input-row (i) tile
  const int by = blockIdx.x >> 4;    // output-row (o) tile
  const int r = threadIdx.x >> 4, c4 = threadIdx.x & 15;
#pragma unroll
  for (int i = 0; i < 4; ++i) {
    const int row = bx * 64 + r + i * 16;
    float4 v = *(const float4*)&w[row * 1024 + by * 64 + c4 * 4];
    t[r + i * 16][c4 * 4 + 0] = v.x;
    t[r + i * 16][c4 * 4 + 1] = v.y;
    t[r + i * 16][c4 * 4 + 2] = v.z;
    t[r + i * 16][c4 * 4 + 3] = v.w;
  }
  __syncthreads();
  const int l = threadIdx.x & 63, og = threadIdx.x >> 6;
#pragma unroll
  for (int j = 0; j < 16; ++j) {
    const int o_local = og + j * 4;
    t16[(by * 64 + o_local) * 1024 + bx * 64 + l] = f2h(t[l][o_local]);
  }
}

// memory-slot rows of K (keys 1024..1039 = sqrt(DK)*m_k ; 1040..1087 = 0)
__global__ void mk_fill_kernel(const float* __restrict__ m_k, u16* __restrict__ kh) {
  int idx = blockIdx.x * 256 + threadIdx.x;     // 64*64*128 = 524288
  int bh = idx >> 13, ko = (idx >> 7) & 63, dk = idx & 127;
  int h = bh & 7;
  float v = 0.f;
  if (ko < 16) v = 11.313708498984760f * m_k[ko * 1024 + h * 128 + dk];
  kh[((size_t)bh * KSP + 1024 + ko) * 128 + dk] = f2h(v);
}

// memory-slot keys of V^T (keys 1024..1039 = sqrt(M)*m_v ; 1040..1087 = 0)
__global__ void mv_fill_kernel(const float* __restrict__ m_v, u16* __restrict__ vt) {
  int idx = blockIdx.x * 256 + threadIdx.x;     // 64*128*64 = 524288
  int bh = idx >> 13, dv = (idx >> 6) & 127, ko = idx & 63;
  int h = bh & 7;
  float v = (ko < 16) ? 4.0f * m_v[ko * 1024 + h * 128 + dv] : 0.f;
  vt[((size_t)bh * 128 + dv) * KSP + 1024 + ko] = f2h(v);
}

// mask (int32, !=0 dead) -> bit words. mbits[(bh*1024+q)*34 + w].
__global__ void maskbits_kernel(const int* __restrict__ mask, u32* __restrict__ mbits) {
  const int lane = threadIdx.x & 63;
  const int nwave = (gridDim.x * blockDim.x) >> 6;
  int wid = (blockIdx.x * blockDim.x + threadIdx.x) >> 6;
  for (int g = wid; g < 262144; g += nwave) {       // 256-key groups
    const int4 m = *(const int4*)&mask[(size_t)g * 256 + lane * 4];
    u32 nib = (m.x ? 1u : 0u) | (m.y ? 2u : 0u) | (m.z ? 4u : 0u) | (m.w ? 8u : 0u);
    u32 v = nib << ((lane & 7) * 4);
    v |= __shfl_xor(v, 1);
    v |= __shfl_xor(v, 2);
    v |= __shfl_xor(v, 4);
    if ((lane & 7) == 0) {
      const int row = g >> 2;                        // (bh*1024+q)
      const int word = ((g & 3) << 3) + (lane >> 3); // 0..31
      mbits[row * MW + word] = v;
    }
  }
}

// word 32: keys 1024..1039 alive, 1040..1055 dead; word 33: all dead
__global__ void maskfill_kernel(u32* __restrict__ mbits) {
  int idx = blockIdx.x * 256 + threadIdx.x;   // 65536
  mbits[idx * MW + 32] = 0xFFFF0000u;
  mbits[idx * MW + 33] = 0xFFFFFFFFu;
}

// ---------------------------------------------------------------------- GEMM
// C(8192x1024) = A(8192x1024) @ B^T, B given as (1024 n-rows x 1024 k) rm.
// 128x128 tile, BK=64, 4 waves (2x2), 4x4 16x16x32 fp16 fragments per wave.
__device__ __forceinline__ void stage_tile(const u16* __restrict__ gbase,
                                           u16* sbase, int w, int lane) {
#pragma unroll
  for (int i = 0; i < 4; ++i) {
    const u16* src = gbase + (w * 32 + i * 8 + (lane >> 3)) * 1024 + (lane & 7) * 8;
    u16* dst = sbase + (w * 32 + i * 8) * 64;
    __builtin_amdgcn_global_load_lds(
        (const __attribute__((address_space(1))) void*)src,
        (__attribute__((address_space(3))) void*)dst, 16, 0, 0);
  }
}

enum { EPI_Q16 = 0, EPI_K16 = 1, EPI_VT = 2, EPI_OUT = 3 };

template <int EPI>
__global__ __launch_bounds__(256)
void gemm_kernel(const u16* __restrict__ A, const u16* __restrict__ B,
                 const float* __restrict__ bias,
                 u16* __restrict__ oH, float* __restrict__ oF) {
  __shared__ u16 sA[128 * 64];
  __shared__ u16 sB[128 * 64];
  const int lane = threadIdx.x & 63, w = threadIdx.x >> 6;
  const int bm = blockIdx.x & 63, bn = blockIdx.x >> 6;
  const int wr = w >> 1, wc = w & 1;

  f32x4 acc[4][4];
  const f32x4 fz = {0.f, 0.f, 0.f, 0.f};
#pragma unroll
  for (int m = 0; m < 4; ++m)
#pragma unroll
    for (int n = 0; n < 4; ++n) acc[m][n] = fz;

  for (int kt = 0; kt < 16; ++kt) {
    const int kb = kt * 64;
    stage_tile(A + bm * 128 * 1024 + kb, sA, w, lane);
    stage_tile(B + bn * 128 * 1024 + kb, sB, w, lane);
    __syncthreads();
    const int ro = lane & 15;
#pragma unroll
    for (int kk = 0; kk < 2; ++kk) {
      const int co = kk * 32 + (lane >> 4) * 8;
      f16x8 a[4], b[4];
#pragma unroll
      for (int m = 0; m < 4; ++m) a[m] = ld_h8(&sA[(wr * 64 + m * 16 + ro) * 64 + co]);
#pragma unroll
      for (int n = 0; n < 4; ++n) b[n] = ld_h8(&sB[(wc * 64 + n * 16 + ro) * 64 + co]);
#pragma unroll
      for (int m = 0; m < 4; ++m)
#pragma unroll
        for (int n = 0; n < 4; ++n)
          acc[m][n] = MFMA_F16(a[m], b[n], acc[m][n]);
    }
    __syncthreads();
  }

  // epilogue
#pragma unroll
  for (int m = 0; m < 4; ++m)
#pragma unroll
    for (int n = 0; n < 4; ++n) {
      const int row0 = bm * 128 + wr * 64 + m * 16 + ((lane >> 4) << 2);
      const int col = bn * 128 + wc * 64 + n * 16 + (lane & 15);
      const float bv = bias[col];
#pragma unroll
      for (int r = 0; r < 4; ++r) {
        const float y = acc[m][n][r] + bv;
        const int row = row0 + r;
        if constexpr (EPI == EPI_Q16) {
          oH[row * 1024 + col] = f2h(y);
        } else if constexpr (EPI == EPI_K16) {
          const int b = row >> 10, key = row & 1023;
          oH[((size_t)(b * 8 + (col >> 7)) * KSP + key) * 128 + (col & 127)] = f2h(y);
        } else if constexpr (EPI == EPI_VT) {
          const int b = row >> 10, key = row & 1023;
          oH[((size_t)(b * 8 + (col >> 7)) * 128 + (col & 127)) * KSP + key] = f2h(y);
        } else {
          oF[row * 1024 + col] = y;
        }
      }
    }
}

// ----------------------------------------------------------------- attention
// 4 waves/block, 16 q-rows/wave, 1024 blocks (64 bh x 16 qblk, bh-per-XCD).
// Phase 1: 17 x 64-key chunks, QK^T+exp -> lsum only. Shuffle-reduce ->
// inv[4] in regs. Phase 2: 17 x 64-key chunks, QK^T recomputed (K L2-hot),
// e*inv -> normalized att + PV. T14 reg-staging, XOR-swizzled K LDS.
// O written via LDS re-tile (coalesced 16B stores).
__global__ __launch_bounds__(256, 3)
void attn_kernel(const u16* __restrict__ qh, const u16* __restrict__ kh,
                 const u16* __restrict__ vt, const u32* __restrict__ mbits,
                 float* __restrict__ att, u16* __restrict__ obuf) {
  __shared__ __align__(16) u16 sK[64 * 128];        // 16 KB
  __shared__ __align__(16) u16 sV[128 * 72];        // 18 KB (144B rows)
  __shared__ __align__(16) float sAtt[4][16][36];   // 9 KB
  const int tid = threadIdx.x;
  const int lane = tid & 63, w = tid >> 6;

  // XCD swizzle: XCD x owns bh in [x*8, x*8+8), 16 qblks each.
  const int d = blockIdx.x;                  // 1024 blocks
  const int j = d >> 3;
  const int bh = (d & 7) * 8 + (j >> 4);
  const int qblk = j & 15;
  const int h = bh & 7;
  const int b = bh >> 3;
  const int qrow0 = qblk * 64 + w * 16;       // within NQ
  const int grow0 = b * NQS + qrow0;          // row in (8192 x 1024) Q/O buffers
  const int ro = lane & 15, go = lane >> 4;

  // Q fragments (held for whole kernel)
  f16x8 qf[4];
#pragma unroll
  for (int kk = 0; kk < 4; ++kk)
    qf[kk] = ld_h8(&qh[(grow0 + ro) * 1024 + h * 128 + kk * 32 + go * 8]);

  const u16* khb = kh + (size_t)bh * KSP * 128;
  const u16* vtb = vt + (size_t)bh * 128 * KSP;
  const u32* mbb = mbits + (size_t)bh * NQS * MW;
  float* attb = att + (size_t)(bh * NQS + qrow0) * NKM;

  // K staging geometry: 4 x 16B per thread (rows r_k, +16, +32, +48)
  const int r_k  = tid >> 4;               // 0..15
  const int cb_k = (tid & 15) * 16;        // byte col in 256B row
  const u16* kp0 = khb + r_k * 128 + (cb_k >> 1);
  const int dk0 = r_k * 256 + (cb_k ^ ((r_k & 7) << 4));   // xor invariant to +16 rows
  // V staging geometry: 4 x 16B per thread; t = p*256+tid: row t>>3, chunk t&7
  const int vrow[4] = {(0 * 256 + tid) >> 3, (1 * 256 + tid) >> 3,
                       (2 * 256 + tid) >> 3, (3 * 256 + tid) >> 3};
  const int vc8[4]  = {(0 * 256 + tid) & 7, (1 * 256 + tid) & 7,
                       (2 * 256 + tid) & 7, (3 * 256 + tid) & 7};

  const f32x4 fz = {0.f, 0.f, 0.f, 0.f};
  float lsum[4] = {0.f, 0.f, 0.f, 0.f};

  // ================= phase 1: row sums (17 x 64-key chunks) ===============
  {
    s16x8 rk0 = *(const s16x8*)(kp0);
    s16x8 rk1 = *(const s16x8*)(kp0 + 16 * 128);
    s16x8 rk2 = *(const s16x8*)(kp0 + 32 * 128);
    s16x8 rk3 = *(const s16x8*)(kp0 + 48 * 128);
    for (int c = 0; c < 17; ++c) {
      __syncthreads();
      *(s16x8*)((char*)sK + dk0)         = rk0;
      *(s16x8*)((char*)sK + dk0 + 4096)  = rk1;
      *(s16x8*)((char*)sK + dk0 + 8192)  = rk2;
      *(s16x8*)((char*)sK + dk0 + 12288) = rk3;
      if (c < 16) {
        const u16* p = kp0 + (c + 1) * 64 * 128;
        rk0 = *(const s16x8*)(p);
        rk1 = *(const s16x8*)(p + 16 * 128);
        rk2 = *(const s16x8*)(p + 32 * 128);
        rk3 = *(const s16x8*)(p + 48 * 128);
      }
      __syncthreads();
      u32 mw0[4], mw1[4];
#pragma unroll
      for (int r = 0; r < 4; ++r) {
        const int row = qrow0 + (go << 2) + r;
        mw0[r] = mbb[row * MW + 2 * c];
        mw1[r] = mbb[row * MW + 2 * c + 1];
      }
#pragma unroll
      for (int t = 0; t < 4; ++t) {
        f32x4 s = fz;
        const int rr = t * 16 + ro;
        const int sw = (rr & 7) << 4;
        __builtin_amdgcn_s_setprio(1);
#pragma unroll
        for (int kk = 0; kk < 4; ++kk) {
          const int off = rr * 256 + ((kk * 64 + go * 16) ^ sw);
          s = MFMA_F16(qf[kk], ld_h8((const u16*)((const char*)sK + off)), s);
        }
        __builtin_amdgcn_s_setprio(0);
        const int bit = (t & 1) * 16 + ro;
#pragma unroll
        for (int r = 0; r < 4; ++r) {
          const u32 mw = (t < 2) ? mw0[r] : mw1[r];
          const bool dead = (mw >> bit) & 1;
          lsum[r] += dead ? 0.f : __expf(s[r] * SCALE_QK);
        }
      }
    }
  }

  // reduce across the 16 ro-lanes of each go-group -> every lane holds inv[]
  float inv[4];
#pragma unroll
  for (int r = 0; r < 4; ++r) {
    lsum[r] += __shfl_xor(lsum[r], 1);
    lsum[r] += __shfl_xor(lsum[r], 2);
    lsum[r] += __shfl_xor(lsum[r], 4);
    lsum[r] += __shfl_xor(lsum[r], 8);
    inv[r] = 1.0f / lsum[r];
  }

  // ================= phase 2: normalized att + PV =========================
  f32x4 oacc[8];
#pragma unroll
  for (int n = 0; n < 8; ++n) oacc[n] = fz;

  s16x8 rk0 = *(const s16x8*)(kp0);
  s16x8 rk1 = *(const s16x8*)(kp0 + 16 * 128);
  s16x8 rk2 = *(const s16x8*)(kp0 + 32 * 128);
  s16x8 rk3 = *(const s16x8*)(kp0 + 48 * 128);
  s16x8 rv0 = *(const s16x8*)(vtb + (size_t)vrow[0] * KSP + vc8[0] * 8);
  s16x8 rv1 = *(const s16x8*)(vtb + (size_t)vrow[1] * KSP + vc8[1] * 8);
  s16x8 rv2 = *(const s16x8*)(vtb + (size_t)vrow[2] * KSP + vc8[2] * 8);
  s16x8 rv3 = *(const s16x8*)(vtb + (size_t)vrow[3] * KSP + vc8[3] * 8);

  for (int c = 0; c < 17; ++c) {
    __syncthreads();                       // previous chunk fully consumed
    *(s16x8*)((char*)sK + dk0)         = rk0;
    *(s16x8*)((char*)sK + dk0 + 4096)  = rk1;
    *(s16x8*)((char*)sK + dk0 + 8192)  = rk2;
    *(s16x8*)((char*)sK + dk0 + 12288) = rk3;
    *(s16x8*)((char*)sV + vrow[0] * 144 + vc8[0] * 16) = rv0;
    *(s16x8*)((char*)sV + vrow[1] * 144 + vc8[1] * 16) = rv1;
    *(s16x8*)((char*)sV + vrow[2] * 144 + vc8[2] * 16) = rv2;
    *(s16x8*)((char*)sV + vrow[3] * 144 + vc8[3] * 16) = rv3;
    if (c < 16) {                          // issue next chunk's loads
      const int nkb = (c + 1) * 64;
      const u16* p = kp0 + nkb * 128;
      rk0 = *(const s16x8*)(p);
      rk1 = *(const s16x8*)(p + 16 * 128);
      rk2 = *(const s16x8*)(p + 32 * 128);
      rk3 = *(const s16x8*)(p + 48 * 128);
      rv0 = *(const s16x8*)(vtb + (size_t)vrow[0] * KSP + nkb + vc8[0] * 8);
      rv1 = *(const s16x8*)(vtb + (size_t)vrow[1] * KSP + nkb + vc8[1] * 8);
      rv2 = *(const s16x8*)(vtb + (size_t)vrow[2] * KSP + nkb + vc8[2] * 8);
      rv3 = *(const s16x8*)(vtb + (size_t)vrow[3] * KSP + nkb + vc8[3] * 8);
    }
    __syncthreads();                       // chunk c ready

    u32 mwc[2][4];
#pragma unroll
    for (int r = 0; r < 4; ++r) {
      const int row = qrow0 + (go << 2) + r;
      mwc[0][r] = mbb[row * MW + 2 * c];
      mwc[1][r] = mbb[row * MW + 2 * c + 1];
    }

#pragma unroll
    for (int t2 = 0; t2 < 2; ++t2) {
#pragma unroll
      for (int t = 0; t < 2; ++t) {
        f32x4 s = fz;
        const int rr = t2 * 32 + t * 16 + ro;        // key row in 64-chunk
        const int sw = (rr & 7) << 4;
        __builtin_amdgcn_s_setprio(1);
#pragma unroll
        for (int kk = 0; kk < 4; ++kk) {
          const int off = rr * 256 + ((kk * 64 + go * 16) ^ sw);
          s = MFMA_F16(qf[kk], ld_h8((const u16*)((const char*)sK + off)), s);
        }
        __builtin_amdgcn_s_setprio(0);
        const int bit = t * 16 + ro;
#pragma unroll
        for (int r = 0; r < 4; ++r) {
          const int lrow = (go << 2) + r;
          const bool dead = (mwc[t2][r] >> bit) & 1;
          const float e = dead ? 0.f : __expf(s[r] * SCALE_QK);
          sAtt[w][lrow][t * 16 + ro] = e * inv[r];   // normalized
        }
      }

      // att writeout (normalized): 4 lanes cover one row's 32 f32 (128B)
      {
        const int kbh = c * 64 + t2 * 32;
        const int arow = lane >> 2, cg = lane & 3;
        if (kbh + cg * 8 < NKM) {
          f32x4 v0 = *(const f32x4*)&sAtt[w][arow][cg * 8];
          f32x4 v1 = *(const f32x4*)&sAtt[w][arow][cg * 8 + 4];
          float* dst = attb + (size_t)arow * NKM + kbh + cg * 8;
          *(f32x4*)dst = v0;
          *(f32x4*)(dst + 4) = v1;
        }
      }

      // PV with normalized p (A rows=q, cols=key), B rows=dv from sV
      {
        f32x4 p0 = *(const f32x4*)&sAtt[w][ro][go * 8];
        f32x4 p1 = *(const f32x4*)&sAtt[w][ro][go * 8 + 4];
        f16x8 pa;
        pa[0] = (_Float16)p0[0]; pa[1] = (_Float16)p0[1];
        pa[2] = (_Float16)p0[2]; pa[3] = (_Float16)p0[3];
        pa[4] = (_Float16)p1[0]; pa[5] = (_Float16)p1[1];
        pa[6] = (_Float16)p1[2]; pa[7] = (_Float16)p1[3];
        __builtin_amdgcn_s_setprio(1);
#pragma unroll
        for (int n = 0; n < 8; ++n) {
          f16x8 vb = ld_h8((const u16*)((const char*)sV + (n * 16 + ro) * 144 + t2 * 64 + go * 16));
          oacc[n] = MFMA_F16(pa, vb, oacc[n]);
        }
        __builtin_amdgcn_s_setprio(0);
      }
    }
  }

  // O writeout via LDS re-tile: wave w stages 16 rows x 128 cols fp16 at
  // sK + w*4096, then 16B coalesced stores (16 lanes cover one 256B row).
  __syncthreads();
  {
    u16* os = (u16*)((char*)sK + w * 4096);
#pragma unroll
    for (int n = 0; n < 8; ++n)
#pragma unroll
      for (int r = 0; r < 4; ++r)
        os[((go << 2) + r) * 128 + n * 16 + ro] = f2h(oacc[n][r]);
#pragma unroll
    for (int i = 0; i < 4; ++i) {
      const int idx = i * 64 + lane;            // 0..255
      const int row = idx >> 4, c16 = idx & 15; // 16 rows x 16 chunks
      s16x8 v = *(const s16x8*)(os + row * 128 + c16 * 8);
      *(s16x8*)&obuf[(size_t)(grow0 + row) * 1024 + h * 128 + c16 * 8] = v;
    }
  }
}

// --------------------------------------------------------------------- launch
extern "C" void kernel_launch(void* const* d_in, const int* in_sizes, int n_in,
                              void* d_out, int out_size, void* d_ws, size_t ws_size,
                              hipStream_t stream) {
  const float* queries = (const float*)d_in[0];
  const float* keys    = (const float*)d_in[1];
  const float* values  = (const float*)d_in[2];
  const int*   mask    = (const int*)d_in[3];
  const float* Wq = (const float*)d_in[4];
  const float* bq = (const float*)d_in[5];
  const float* Wk = (const float*)d_in[6];
  const float* bk = (const float*)d_in[7];
  const float* Wv = (const float*)d_in[8];
  const float* bv = (const float*)d_in[9];
  const float* Wo = (const float*)d_in[10];
  const float* bo = (const float*)d_in[11];
  const float* m_k = (const float*)d_in[12];
  const float* m_v = (const float*)d_in[13];

  if (ws_size < 136839168) return;   // layout below needs ~130.5 MiB

  char* ws = (char*)d_ws;
  u16* xq  = (u16*)(ws + 0);           // 16 MiB
  u16* xk  = (u16*)(ws + 16777216);    // 16 MiB
  u16* xv  = (u16*)(ws + 33554432);    // 16 MiB
  u16* wq  = (u16*)(ws + 50331648);    // 2 MiB
  u16* wk  = (u16*)(ws + 52428800);
  u16* wv  = (u16*)(ws + 54525952);
  u16* wo  = (u16*)(ws + 56623104);
  u16* q16 = (u16*)(ws + 58720256);    // 16 MiB
  u16* k16 = (u16*)(ws + 75497472);    // 64*1088*128*2 = 17 MiB
  u16* vt  = (u16*)(ws + 93323264);    // 17 MiB
  u16* obuf= (u16*)(ws + 111149056);   // 16 MiB
  u32* mbits=(u32*)(ws + 127926272);   // 8.9 MiB

  float* out = (float*)d_out;
  float* att = out + 8388608;

  // 1. input converts (f32 -> fp16)
  cvt16_kernel<<<2048, 256, 0, stream>>>(queries, xq, 2097152);
  cvt16_kernel<<<2048, 256, 0, stream>>>(keys,    xk, 2097152);
  cvt16_kernel<<<2048, 256, 0, stream>>>(values,  xv, 2097152);
  // 2. weight transposes (LDS-tiled, fp16)
  wtrans16_kernel<<<256, 256, 0, stream>>>(Wq, wq);
  wtrans16_kernel<<<256, 256, 0, stream>>>(Wk, wk);
  wtrans16_kernel<<<256, 256, 0, stream>>>(Wv, wv);
  wtrans16_kernel<<<256, 256, 0, stream>>>(Wo, wo);
  // 3. projections (plain fp16 GEMMs)
  gemm_kernel<EPI_Q16><<<512, 256, 0, stream>>>(xq, wq, bq, q16, nullptr);
  gemm_kernel<EPI_K16><<<512, 256, 0, stream>>>(xk, wk, bk, k16, nullptr);
  gemm_kernel<EPI_VT> <<<512, 256, 0, stream>>>(xv, wv, bv, vt,  nullptr);
  // 4. mask bit-pack
  maskbits_kernel<<<2048, 256, 0, stream>>>(mask, mbits);
  maskfill_kernel<<<256, 256, 0, stream>>>(mbits);
  // 5. memory slots (K rows 1024..1087, V^T keys 1024..1087)
  mk_fill_kernel<<<2048, 256, 0, stream>>>(m_k, k16);
  mv_fill_kernel<<<2048, 256, 0, stream>>>(m_v, vt);
  // 6. attention (normalized att + O in one kernel, two-pass over K)
  attn_kernel<<<1024, 256, 0, stream>>>(q16, k16, vt, mbits, att, obuf);
  // 7. output projection
  gemm_kernel<EPI_OUT><<<512, 256, 0, stream>>>(obuf, wo, bo, nullptr, out);
}